// Round 8
// baseline (567.689 us; speedup 1.0000x reference)
//
#include <hip/hip_runtime.h>
#include <math.h>

#define GG   10000
#define NN0  32
#define EE0  64
#define NFF  64
#define HH   128
#define DD   256
#define BB   4096
#define E2B  8192
#define SIXH 768

// ============================================================
// Wave-per-graph fused pipeline. 4 independent waves per block,
// ZERO __syncthreads. Per-wave LDS (13.5 KB): y-transit buffer,
// rectangular adjacency A[32][36] (cols = prev-stage index space),
// small score/rank arrays. All feature tensors live in registers
// with static indexing; pooling handled via A-column remap + A+=I
// self-loop fold. Wave-synchronous LDS ordering via wave_barrier
// (compiler fence) + in-order DS pipe.
// ============================================================

#define WSYNC() do { __builtin_amdgcn_wave_barrier(); __builtin_amdgcn_sched_barrier(0); } while (0)

// per-wave LDS float offsets
#define OF_A   2048   // [32][36] = 1152
#define OF_DIS 3200
#define OF_CMO 3232   // also reused as v1e
#define OF_SCO 3264
#define OF_RNK 3296   // int[32]
#define OF_INV 3328   // int[16]
#define OF_V1  3344   // [32]
#define LWSZ   3376   // floats per wave

template<int M, int P, int K, int J, int KK, bool FIRST, bool LAST>
__device__ __forceinline__ void stage(
    const float* __restrict__ Wg, const float* __restrict__ bg,
    const float* __restrict__ Wr, const float* __restrict__ Wn,
    const float* __restrict__ bs,
    float* yb, float* A, float* disL, float* cmoL, float* scoL,
    int* rnkL, int* invL, float* v1L,
    float (&xh)[P][J], float (&outr)[M][2],
    int& srcC, int& dstC, int& srcP, float& ew,
    float* __restrict__ featg, const int lane)
{
  // ---- build A[dstC][srcP] += ew (A pre-zeroed; one edge per lane)
  atomicAdd(&A[dstC*36 + srcP], ew);
  WSYNC();
  // ---- deg = 1 + rowsum(A) -> dis  (BEFORE A += I)
  if (lane < M) {
    float deg = 1.f;
#pragma unroll
    for (int m0 = 0; m0 < P; m0 += 4) {
      const float4 a4 = *(const float4*)(A + lane*36 + m0);
      deg += (a4.x + a4.y) + (a4.z + a4.w);
    }
    disL[lane] = rsqrtf(deg);
  }
  WSYNC();
  // ---- A += I at [r][inv_prev[r]] (self-loop fold); cmo = dis[rank]*score gate
  if (lane < M) {
    const int c = FIRST ? lane : invL[lane];
    A[lane*36 + c] += 1.f;
  }
  if (!FIRST && lane < P) {
    const int rk = rnkL[lane];
    cmoL[lane] = (rk < M) ? disL[rk] * scoL[lane] : 0.f;
  }
  WSYNC();
  // ---- fold x̃ = cmo * x̂ (registers)
#pragma unroll
  for (int m0 = 0; m0 < P; m0 += 4) {
    const float4 c4 = *(const float4*)((FIRST ? disL : cmoL) + m0);
#pragma unroll
    for (int q = 0; q < 4; ++q) {
      const float cm = (q==0)?c4.x:(q==1)?c4.y:(q==2)?c4.z:c4.w;
#pragma unroll
      for (int j = 0; j < J; ++j) xh[m0+q][j] *= cm;
    }
  }
  // ---- mix: y[r][k(lane)] = dis_r * sum_m Aplus[r][m] * x̃[m]   (rolled r)
#pragma unroll 1
  for (int r = 0; r < M; ++r) {
    float a0 = 0.f, a1 = 0.f;
#pragma unroll
    for (int m0 = 0; m0 < P; m0 += 4) {
      const float4 a4 = *(const float4*)(A + r*36 + m0);
#pragma unroll
      for (int q = 0; q < 4; ++q) {
        const float aq = (q==0)?a4.x:(q==1)?a4.y:(q==2)?a4.z:a4.w;
        a0 = fmaf(aq, xh[m0+q][0], a0);
        if constexpr (J == 2) a1 = fmaf(aq, xh[m0+q][1], a1);
      }
    }
    const float dr = disL[r];
    if constexpr (J == 1) {
      yb[r*K + lane] = a0 * dr;
    } else {
      float2 v; v.x = a0*dr; v.y = a1*dr;
      *(float2*)(yb + r*K + 2*lane) = v;
    }
  }
  WSYNC();
  // ---- P3: out[r][c2] = sum_k y[r][k] * W[k][c2]   (rolled k, W double-buffered)
#pragma unroll
  for (int r = 0; r < M; ++r) { outr[r][0] = 0.f; outr[r][1] = 0.f; }
  {
    float2 cw0 = *(const float2*)(Wg + 0*HH + 2*lane);
    float2 cw1 = *(const float2*)(Wg + 1*HH + 2*lane);
    float2 cw2 = *(const float2*)(Wg + 2*HH + 2*lane);
    float2 cw3 = *(const float2*)(Wg + 3*HH + 2*lane);
#pragma unroll 1
    for (int k0 = 0; k0 < K; k0 += 4) {
      const int kn = (k0 + 4 < K) ? (k0 + 4) : 0;
      const float2 nw0 = *(const float2*)(Wg + (size_t)(kn+0)*HH + 2*lane);
      const float2 nw1 = *(const float2*)(Wg + (size_t)(kn+1)*HH + 2*lane);
      const float2 nw2 = *(const float2*)(Wg + (size_t)(kn+2)*HH + 2*lane);
      const float2 nw3 = *(const float2*)(Wg + (size_t)(kn+3)*HH + 2*lane);
#pragma unroll
      for (int r = 0; r < M; ++r) {
        const float4 y4 = *(const float4*)(yb + r*K + k0);
        outr[r][0] = fmaf(y4.x, cw0.x, outr[r][0]);
        outr[r][1] = fmaf(y4.x, cw0.y, outr[r][1]);
        outr[r][0] = fmaf(y4.y, cw1.x, outr[r][0]);
        outr[r][1] = fmaf(y4.y, cw1.y, outr[r][1]);
        outr[r][0] = fmaf(y4.z, cw2.x, outr[r][0]);
        outr[r][1] = fmaf(y4.z, cw2.y, outr[r][1]);
        outr[r][0] = fmaf(y4.w, cw3.x, outr[r][0]);
        outr[r][1] = fmaf(y4.w, cw3.y, outr[r][1]);
      }
      cw0 = nw0; cw1 = nw1; cw2 = nw2; cw3 = nw3;
    }
  }
  // ---- epilogue: relu + bias; v1 = out.Wn, v2 = out.Wr (64-lane butterfly)
  const float2 bb  = *(const float2*)(bg + 2*lane);
  const float2 wn  = *(const float2*)(Wn + 2*lane);
  const float2 wrv = *(const float2*)(Wr + 2*lane);
  float v1t = 0.f, v2t = 0.f;
#pragma unroll
  for (int r = 0; r < M; ++r) {
    const float o0 = fmaxf(outr[r][0] + bb.x, 0.f);
    const float o1 = fmaxf(outr[r][1] + bb.y, 0.f);
    outr[r][0] = o0; outr[r][1] = o1;
    float p1 = o0*wn.x + o1*wn.y;
    float p2 = o0*wrv.x + o1*wrv.y;
#pragma unroll
    for (int off = 32; off >= 1; off >>= 1) {
      p1 += __shfl_xor(p1, off);
      p2 += __shfl_xor(p2, off);
    }
    if (lane == r) { v1t = p1; v2t = p2; }
  }
  if (lane < M) v1L[lane] = v1t;
  WSYNC();
  // ---- v1e[m] = v1[rank_prev[m]] (reuse cmoL); FIRST uses v1L directly
  if (!FIRST && lane < P) {
    const int rk = rnkL[lane];
    cmoL[lane] = (rk < M) ? v1L[rk] : 0.f;
  }
  WSYNC();
  // ---- score[t] = tanh(A_raw@v1 + v2 + b)  (Aplus minus the +I term = -v1t)
  float mysc = -2.f;
  if (lane < M) {
    float sc = bs[0] + v2t - v1t;
    const float* v1e = FIRST ? v1L : cmoL;
#pragma unroll
    for (int m0 = 0; m0 < P; m0 += 4) {
      const float4 a4 = *(const float4*)(A + lane*36 + m0);
      const float4 v4 = *(const float4*)(v1e + m0);
      sc += (a4.x*v4.x + a4.y*v4.y) + (a4.z*v4.z + a4.w*v4.w);
    }
    mysc = tanhf(sc);
    scoL[lane] = mysc;
  }
  WSYNC();
  // ---- rank (jax.lax.top_k order, ties -> lower index) + inverse perm
  if (lane < M) {
    int rk = 0;
#pragma unroll
    for (int m0 = 0; m0 < M; m0 += 4) {
      const float4 s4 = *(const float4*)(scoL + m0);
#pragma unroll
      for (int q = 0; q < 4; ++q) {
        const float sm = (q==0)?s4.x:(q==1)?s4.y:(q==2)?s4.z:s4.w;
        rk += (sm > mysc) || (sm == mysc && (m0+q) < lane);
      }
    }
    rnkL[lane] = rk;
    if (rk < KK) invL[rk] = lane;
  }
  WSYNC();
  // ---- readout (gmp || gap) over gated kept rows
  {
    float mx0 = -INFINITY, mx1 = -INFINITY, sm0 = 0.f, sm1 = 0.f;
#pragma unroll
    for (int m0 = 0; m0 < M; m0 += 4) {
      const int4   r4 = *(const int4*)(rnkL + m0);
      const float4 s4 = *(const float4*)(scoL + m0);
#pragma unroll
      for (int q = 0; q < 4; ++q) {
        const int   rq = (q==0)?r4.x:(q==1)?r4.y:(q==2)?r4.z:r4.w;
        const float sq = (q==0)?s4.x:(q==1)?s4.y:(q==2)?s4.z:s4.w;
        const float w0 = outr[m0+q][0] * sq;
        const float w1 = outr[m0+q][1] * sq;
        if (rq < KK) {
          mx0 = fmaxf(mx0, w0); mx1 = fmaxf(mx1, w1);
          sm0 += w0; sm1 += w1;
        }
      }
    }
    float2 vmx; vmx.x = mx0; vmx.y = mx1;
    float2 vsm; vsm.x = sm0 * (1.f/KK); vsm.y = sm1 * (1.f/KK);
    *(float2*)(featg + 2*lane) = vmx;
    *(float2*)(featg + HH + 2*lane) = vsm;
  }
  // ---- remap edge to next stage spaces; zero A for next build
  if constexpr (!LAST) {
    const int rs = rnkL[srcC];
    const int rd = rnkL[dstC];
    const bool val = (rs < KK) && (rd < KK);
    ew   = val ? ew : 0.f;
    srcP = val ? srcC : 0;   // column: current (soon prev) space
    srcC = val ? rs : 0;     // next current space
    dstC = val ? rd : 0;
    WSYNC();
    const float4 z4 = {0.f, 0.f, 0.f, 0.f};
#pragma unroll
    for (int q = 0; q < 5; ++q) {
      const int idx = q*64 + lane;
      if (idx < 288) *(float4*)(A + idx*4) = z4;
    }
    WSYNC();
  }
}

__global__ __launch_bounds__(256, 3) void graph_kernel(
    const float* __restrict__ x,
    const int* __restrict__ esrc, const int* __restrict__ edst, const float* __restrict__ ewg,
    const float* __restrict__ W1, const float* __restrict__ b1,
    const float* __restrict__ Ws1r, const float* __restrict__ Ws1n, const float* __restrict__ bs1,
    const float* __restrict__ W2, const float* __restrict__ b2,
    const float* __restrict__ Ws2r, const float* __restrict__ Ws2n, const float* __restrict__ bs2,
    const float* __restrict__ W3, const float* __restrict__ b3,
    const float* __restrict__ Ws3r, const float* __restrict__ Ws3n, const float* __restrict__ bs3,
    float* __restrict__ feat)
{
  __shared__ __align__(16) float S[4*LWSZ];
  const int lane = threadIdx.x & 63;
  const int w    = threadIdx.x >> 6;
  const int g    = blockIdx.x*4 + w;

  float* lds  = S + w*LWSZ;
  float* yb   = lds;
  float* A    = lds + OF_A;
  float* disL = lds + OF_DIS;
  float* cmoL = lds + OF_CMO;
  float* scoL = lds + OF_SCO;
  int*   rnkL = (int*)(lds + OF_RNK);
  int*   invL = (int*)(lds + OF_INV);
  float* v1L  = lds + OF_V1;

  // zero A
  {
    const float4 z4 = {0.f, 0.f, 0.f, 0.f};
#pragma unroll
    for (int q = 0; q < 5; ++q) {
      const int idx = q*64 + lane;
      if (idx < 288) *(float4*)(A + idx*4) = z4;
    }
  }
  // x -> k-distributed registers (lane = k column)
  float xh1[NN0][1];
#pragma unroll
  for (int m = 0; m < NN0; ++m)
    xh1[m][0] = x[(size_t)g*(NN0*NFF) + m*NFF + lane];
  // one edge per lane
  const int e = g*EE0 + lane;
  int srcC = esrc[e] - g*NN0;
  int dstC = edst[e] - g*NN0;
  int srcP = srcC;
  float ew = ewg[e];
  WSYNC();

  float* featg = feat + (size_t)g * SIXH;

  float out1[32][2];
  stage<32,32, 64,1,16,true ,false>(W1,b1,Ws1r,Ws1n,bs1, yb,A,disL,cmoL,scoL,rnkL,invL,v1L,
                                    xh1, out1, srcC,dstC,srcP,ew, featg, lane);
  float out2[16][2];
  stage<16,32,128,2, 8,false,false>(W2,b2,Ws2r,Ws2n,bs2, yb,A,disL,cmoL,scoL,rnkL,invL,v1L,
                                    out1, out2, srcC,dstC,srcP,ew, featg+256, lane);
  float out3[8][2];
  stage< 8,16,128,2, 4,false,true >(W3,b3,Ws3r,Ws3n,bs3, yb,A,disL,cmoL,scoL,rnkL,invL,v1L,
                                    out2, out3, srcC,dstC,srcP,ew, featg+512, lane);
}

// ============================================================
// DDI stage (unchanged)
// ============================================================

__global__ void k_deg_init(float* __restrict__ degf) {
  int i = blockIdx.x*256 + threadIdx.x;
  if (i < GG) degf[i] = 1.f;
}

__global__ void k_deg_acc(const int* __restrict__ ddi, float* __restrict__ degf) {
  int e = blockIdx.x*256 + threadIdx.x;
  if (e < E2B) atomicAdd(&degf[ddi[E2B + e]], 1.f);
}

// hdd[G,256] = feat[G,768] @ Wd[768,256]; 12 rows/block -> 834 blocks
__global__ __launch_bounds__(256, 4) void k_ddi_gemm(const float* __restrict__ feat,
    const float* __restrict__ Wd, float* __restrict__ hdd)
{
  __shared__ __align__(16) float s_f[12*SIXH];
  const int t = threadIdx.x;
  const int r0 = blockIdx.x * 12;
  const int cg = t & 63, rg = t >> 6;
  for (int idx = t; idx < 12*SIXH/4; idx += 256) {
    const int row = idx / 192;
    float4 v; v.x = 0.f; v.y = 0.f; v.z = 0.f; v.w = 0.f;
    if (r0 + row < GG) v = *(const float4*)(feat + (size_t)r0*SIXH + idx*4);
    *(float4*)(s_f + idx*4) = v;
  }
  __syncthreads();
  float acc[3][4];
#pragma unroll
  for (int i = 0; i < 3; ++i) { acc[i][0]=0.f; acc[i][1]=0.f; acc[i][2]=0.f; acc[i][3]=0.f; }
#pragma unroll 4
  for (int k = 0; k < SIXH; ++k) {
    const float4 w = *(const float4*)(Wd + (size_t)k*DD + cg*4);
#pragma unroll
    for (int i = 0; i < 3; ++i) {
      const float a = s_f[(rg*3 + i)*SIXH + k];
      acc[i][0]=fmaf(a,w.x,acc[i][0]); acc[i][1]=fmaf(a,w.y,acc[i][1]);
      acc[i][2]=fmaf(a,w.z,acc[i][2]); acc[i][3]=fmaf(a,w.w,acc[i][3]);
    }
  }
#pragma unroll
  for (int i = 0; i < 3; ++i) {
    const int row = r0 + rg*3 + i;
    if (row < GG) {
      float4 v; v.x=acc[i][0]; v.y=acc[i][1]; v.z=acc[i][2]; v.w=acc[i][3];
      *(float4*)(hdd + (size_t)row*DD + cg*4) = v;
    }
  }
}

__global__ void k_z_init(const float* __restrict__ hdd, const float* __restrict__ degf,
                         const float* __restrict__ bd, float* __restrict__ z)
{
  int idx = blockIdx.x*256 + threadIdx.x;
  if (idx < GG*DD) {
    int g = idx >> 8, f = idx & 255;
    z[idx] = hdd[idx] / degf[g] + bd[f];
  }
}

__global__ void k_scatter(const int* __restrict__ ddi, const float* __restrict__ degf,
                          const float* __restrict__ hdd, float* __restrict__ z)
{
  const int t = threadIdx.x;
#pragma unroll
  for (int j = 0; j < 4; ++j) {
    const int e = blockIdx.x*4 + j;
    const int s = ddi[e], d = ddi[E2B + e];
    const float nrm = rsqrtf(degf[s]) * rsqrtf(degf[d]);
    atomicAdd(&z[(size_t)d*DD + t], nrm * hdd[(size_t)s*DD + t]);
  }
}

__global__ __launch_bounds__(256) void k_final(const float* __restrict__ z,
    const int* __restrict__ ddi, const float* __restrict__ attr,
    const float* __restrict__ Wl1, const float* __restrict__ bl1,
    const float* __restrict__ Wl2, const float* __restrict__ bl2,
    const float* __restrict__ Wl3, const float* __restrict__ bl3,
    float* __restrict__ out)
{
  __shared__ __align__(16) float s_u[8*257];
  const int t = threadIdx.x;
  const int e0 = blockIdx.x * 8;
  float lacc[8], acc[8];

  for (int idx = t; idx < 8*256; idx += 256) {
    const int r = idx >> 8, k = idx & 255;
    const int src = ddi[e0 + r];
    s_u[r*257 + k] = fmaxf(z[(size_t)src*DD + k], 0.f);
  }
  __syncthreads();
#pragma unroll
  for (int r = 0; r < 8; ++r) acc[r] = bl1[t];
#pragma unroll 4
  for (int k = 0; k < 256; ++k) {
    const float w = Wl1[(size_t)k*DD + t];
#pragma unroll
    for (int r = 0; r < 8; ++r) acc[r] = fmaf(s_u[r*257 + k], w, acc[r]);
  }
#pragma unroll
  for (int r = 0; r < 8; ++r) {
    const float sx = 1.f / (1.f + expf(-acc[r]));
    lacc[r] = sx;
    const int e = e0 + r;
    if (e < BB) out[12288 + (size_t)e*DD + t] = sx;
  }
  __syncthreads();

  for (int idx = t; idx < 8*256; idx += 256) {
    const int r = idx >> 8, k = idx & 255;
    const int dst = ddi[E2B + e0 + r];
    s_u[r*257 + k] = fmaxf(z[(size_t)dst*DD + k], 0.f);
  }
  __syncthreads();
#pragma unroll
  for (int r = 0; r < 8; ++r) acc[r] = bl2[t];
#pragma unroll 4
  for (int k = 0; k < 256; ++k) {
    const float w = Wl2[(size_t)k*DD + t];
#pragma unroll
    for (int r = 0; r < 8; ++r) acc[r] = fmaf(s_u[r*257 + k], w, acc[r]);
  }
#pragma unroll
  for (int r = 0; r < 8; ++r) lacc[r] -= 1.f / (1.f + expf(-acc[r]));
  __syncthreads();

  for (int idx = t; idx < 8*64; idx += 256) {
    const int r = idx >> 6, k = idx & 63;
    s_u[r*257 + k] = attr[(size_t)(e0 + r)*NFF + k];
  }
  __syncthreads();
#pragma unroll
  for (int r = 0; r < 8; ++r) acc[r] = bl3[t];
#pragma unroll 4
  for (int k = 0; k < 64; ++k) {
    const float w = Wl3[(size_t)k*DD + t];
#pragma unroll
    for (int r = 0; r < 8; ++r) acc[r] = fmaf(s_u[r*257 + k], w, acc[r]);
  }
#pragma unroll
  for (int r = 0; r < 8; ++r) lacc[r] += 1.f / (1.f + expf(-acc[r]));
  __syncthreads();

#pragma unroll
  for (int r = 0; r < 8; ++r) s_u[r*257 + t] = lacc[r]*lacc[r];
  __syncthreads();
  {
    const int row = t >> 5, l = t & 31;
    float s = 0.f;
#pragma unroll
    for (int j = 0; j < 8; ++j) s += s_u[row*257 + l + 32*j];
#pragma unroll
    for (int off = 16; off >= 1; off >>= 1) s += __shfl_xor(s, off);
    if (l == 0) {
      const float nrm = sqrtf(s);
      const int e = e0 + row;
      if (e < BB) out[4096 + e] = nrm;
      else        out[8192 + (e - BB)] = nrm;
    }
  }
}

__global__ void k_loss(float* __restrict__ out) {
  int i = blockIdx.x*256 + threadIdx.x;
  if (i < BB) out[i] = 2.f*(float)DD - out[4096 + i] + 0.5f*out[8192 + i];
}

// ============================================================

extern "C" void kernel_launch(void* const* d_in, const int* in_sizes, int n_in,
                              void* d_out, int out_size, void* d_ws, size_t ws_size,
                              hipStream_t stream)
{
  const float* x    = (const float*)d_in[0];
  const int*   esrc = (const int*)d_in[1];
  const int*   edst = (const int*)d_in[2];
  const float* ewt  = (const float*)d_in[3];
  const int*   ddi  = (const int*)d_in[4];
  const float* attr = (const float*)d_in[5];
  const float* W1   = (const float*)d_in[6];  const float* b1  = (const float*)d_in[7];
  const float* Ws1r = (const float*)d_in[8];  const float* Ws1n= (const float*)d_in[9];  const float* bs1 = (const float*)d_in[10];
  const float* W2   = (const float*)d_in[11]; const float* b2  = (const float*)d_in[12];
  const float* Ws2r = (const float*)d_in[13]; const float* Ws2n= (const float*)d_in[14]; const float* bs2 = (const float*)d_in[15];
  const float* W3   = (const float*)d_in[16]; const float* b3  = (const float*)d_in[17];
  const float* Ws3r = (const float*)d_in[18]; const float* Ws3n= (const float*)d_in[19]; const float* bs3 = (const float*)d_in[20];
  const float* Wd   = (const float*)d_in[21]; const float* bd  = (const float*)d_in[22];
  const float* Wl1  = (const float*)d_in[23]; const float* bl1 = (const float*)d_in[24];
  const float* Wl2  = (const float*)d_in[25]; const float* bl2 = (const float*)d_in[26];
  const float* Wl3  = (const float*)d_in[27]; const float* bl3 = (const float*)d_in[28];

  float* ws   = (float*)d_ws;
  float* feat = ws;
  float* hdd  = feat + (size_t)GG*SIXH;
  float* zb   = hdd  + (size_t)GG*DD;
  float* degf = zb   + (size_t)GG*DD;
  float* out  = (float*)d_out;

  graph_kernel<<<GG/4, 256, 0, stream>>>(x, esrc, edst, ewt,
      W1, b1, Ws1r, Ws1n, bs1, W2, b2, Ws2r, Ws2n, bs2, W3, b3, Ws3r, Ws3n, bs3, feat);
  k_deg_init<<<(GG + 255)/256, 256, 0, stream>>>(degf);
  k_deg_acc<<<(E2B + 255)/256, 256, 0, stream>>>(ddi, degf);
  k_ddi_gemm<<<(GG + 11)/12, 256, 0, stream>>>(feat, Wd, hdd);
  k_z_init<<<(GG*DD + 255)/256, 256, 0, stream>>>(hdd, degf, bd, zb);
  k_scatter<<<E2B/4, 256, 0, stream>>>(ddi, degf, hdd, zb);
  k_final<<<E2B/8, 256, 0, stream>>>(zb, ddi, attr, Wl1, bl1, Wl2, bl2, Wl3, bl3, out);
  k_loss<<<(BB + 255)/256, 256, 0, stream>>>(out);
}

// Round 9
// 521.581 us; speedup vs baseline: 1.0884x; 1.0884x over previous
//
#include <hip/hip_runtime.h>
#include <math.h>

#define GG   10000
#define NN0  32
#define EE0  64
#define NFF  64
#define HH   128
#define DD   256
#define BB   4096
#define E2B  8192
#define SIXH 768
#define APAD 36

// ============================================================
// Per-graph fused pipeline (round-7 structure, verbatim revert):
// aggregate-first, full-K bufY, wave-pair k-split P3, LDS-atomic
// A-build, fused wave-0 score/rank/remap. ~29.6 KB LDS -> 5 blocks/CU.
// ============================================================

template<int M, int KK, int K, int SX, bool IND, bool LAST>
__device__ __forceinline__ void stage(
    const float* __restrict__ Wg, const float* __restrict__ bg,
    const float* __restrict__ Wr, const float* __restrict__ Wn, const float* __restrict__ bs,
    float* bufX, float* bufY, float* s_A,
    float* s_dis, float* s_cm, float* s_sc2,
    float* s_v1, float* s_v2, float* s_score, int* s_rank, int* s_inv,
    int& src_r, int& dst_r, float& ew_r,
    float* __restrict__ featg, int t)
{
  // P0: raw A[dst][src] += ew via LDS atomics (wave 0, one edge per lane)
  if (t < EE0)
    atomicAdd(&s_A[dst_r*APAD + src_r], ew_r);
  __syncthreads();

  // P1: deg = 1 + row-sum(A) -> dis; cm = dis*g; sc2 = dis^2*g
  if (t < M) {
    float deg = 1.f;
#pragma unroll
    for (int m0 = 0; m0 < M; m0 += 4) {
      const float4 a4 = *(const float4*)(s_A + t*APAD + m0);
      deg += a4.x + a4.y + a4.z + a4.w;
    }
    const float dis = rsqrtf(deg);
    const float gg = IND ? s_score[s_inv[t]] : 1.f;
    s_dis[t] = dis; s_cm[t] = dis*gg; s_sc2[t] = dis*dis*gg;
  }
  __syncthreads();

  // P2: y[r] = dis_r * sum_m A[r,m]*cm[m]*x[ind(m)] + sc2[r]*x[ind(r)]  (full K)
  {
    constexpr int CGB = K/4, RGB = 256/CGB, R = M/RGB;
    const int cg = t % CGB, rg = t / CGB;
    const int c0 = cg * 4;
    float acc[R][4];
#pragma unroll
    for (int i = 0; i < R; ++i) { acc[i][0]=0.f; acc[i][1]=0.f; acc[i][2]=0.f; acc[i][3]=0.f; }
#pragma unroll 2
    for (int m0 = 0; m0 < M; m0 += 4) {
      float4 a[R];
#pragma unroll
      for (int i = 0; i < R; ++i)
        a[i] = *(const float4*)(s_A + (rg*R + i)*APAD + m0);
#pragma unroll
      for (int j = 0; j < 4; ++j) {
        const int m = m0 + j;
        const int row = IND ? s_inv[m] : m;
        const float4 xv = *(const float4*)(bufX + row*SX + c0);
        const float cmm = s_cm[m];
#pragma unroll
        for (int i = 0; i < R; ++i) {
          const float aj = (j==0) ? a[i].x : (j==1) ? a[i].y : (j==2) ? a[i].z : a[i].w;
          const float cf = aj * cmm;
          acc[i][0] = fmaf(cf, xv.x, acc[i][0]);
          acc[i][1] = fmaf(cf, xv.y, acc[i][1]);
          acc[i][2] = fmaf(cf, xv.z, acc[i][2]);
          acc[i][3] = fmaf(cf, xv.w, acc[i][3]);
        }
      }
    }
#pragma unroll
    for (int i = 0; i < R; ++i) {
      const int r = rg*R + i;
      const int rr = IND ? s_inv[r] : r;
      const float4 xv = *(const float4*)(bufX + rr*SX + c0);
      const float dr = s_dis[r], sc = s_sc2[r];
      float4 v;
      v.x = fmaf(sc, xv.x, acc[i][0]*dr);
      v.y = fmaf(sc, xv.y, acc[i][1]*dr);
      v.z = fmaf(sc, xv.z, acc[i][2]*dr);
      v.w = fmaf(sc, xv.w, acc[i][3]*dr);
      *(float4*)(bufY + r*K + c0) = v;
    }
  }
  __syncthreads();

  // P3: out = relu(y @ W + b) -> bufX; fused v1 = out.Wn, v2 = out.Wr
  if constexpr (K != HH) {
    constexpr int R = M / 4;
    const int cg = t & 63;
    const int rg = t >> 6;
    float acc0[R], acc1[R];
#pragma unroll
    for (int i = 0; i < R; ++i) { acc0[i]=0.f; acc1[i]=0.f; }
#pragma unroll 2
    for (int k0 = 0; k0 < K; k0 += 4) {
      float4 yv[R];
#pragma unroll
      for (int i = 0; i < R; ++i)
        yv[i] = *(const float4*)(bufY + (rg*R + i)*K + k0);
#pragma unroll
      for (int j = 0; j < 4; ++j) {
        const float2 w = *(const float2*)(Wg + (size_t)(k0+j)*HH + cg*2);
#pragma unroll
        for (int i = 0; i < R; ++i) {
          const float yj = (j==0) ? yv[i].x : (j==1) ? yv[i].y : (j==2) ? yv[i].z : yv[i].w;
          acc0[i] = fmaf(yj, w.x, acc0[i]);
          acc1[i] = fmaf(yj, w.y, acc1[i]);
        }
      }
    }
    const float2 b2  = *(const float2*)(bg + cg*2);
    const float2 wn2 = *(const float2*)(Wn + cg*2);
    const float2 wr2 = *(const float2*)(Wr + cg*2);
#pragma unroll
    for (int i = 0; i < R; ++i) {
      const int row = rg*R + i;
      const float ox = fmaxf(acc0[i] + b2.x, 0.f);
      const float oy = fmaxf(acc1[i] + b2.y, 0.f);
      float2 v; v.x=ox; v.y=oy;
      *(float2*)(bufX + row*HH + cg*2) = v;
      float p1 = ox*wn2.x + oy*wn2.y;
      float p2 = ox*wr2.x + oy*wr2.y;
#pragma unroll
      for (int off = 32; off >= 1; off >>= 1) {
        p1 += __shfl_xor(p1, off);
        p2 += __shfl_xor(p2, off);
      }
      if ((t & 63) == 0) { s_v1[row] = p1; s_v2[row] = p2; }
    }
  } else {
    constexpr int R = M / 2;
    const int cg  = t & 63;
    const int sub = (t >> 6) & 1;
    const int pr  = t >> 7;
    const int kbase = pr * (K/2);
    float acc0[R], acc1[R];
#pragma unroll
    for (int i = 0; i < R; ++i) { acc0[i]=0.f; acc1[i]=0.f; }
#pragma unroll 2
    for (int k0 = 0; k0 < K/2; k0 += 4) {
      float4 yv[R];
#pragma unroll
      for (int i = 0; i < R; ++i)
        yv[i] = *(const float4*)(bufY + (sub*R + i)*K + kbase + k0);
#pragma unroll
      for (int j = 0; j < 4; ++j) {
        const float2 w = *(const float2*)(Wg + (size_t)(kbase+k0+j)*HH + cg*2);
#pragma unroll
        for (int i = 0; i < R; ++i) {
          const float yj = (j==0) ? yv[i].x : (j==1) ? yv[i].y : (j==2) ? yv[i].z : yv[i].w;
          acc0[i] = fmaf(yj, w.x, acc0[i]);
          acc1[i] = fmaf(yj, w.y, acc1[i]);
        }
      }
    }
    __syncthreads();
    float* pdst = pr ? bufY : bufX;
#pragma unroll
    for (int i = 0; i < R; ++i) {
      float2 v; v.x=acc0[i]; v.y=acc1[i];
      *(float2*)(pdst + (sub*R + i)*HH + cg*2) = v;
    }
    __syncthreads();
    constexpr int RE = M / 8;
    const int ecg = t & 31, erg = t >> 5;
    const int f0 = ecg * 4;
    const float4 b4  = *(const float4*)(bg + f0);
    const float4 wn4 = *(const float4*)(Wn + f0);
    const float4 wr4 = *(const float4*)(Wr + f0);
#pragma unroll
    for (int i = 0; i < RE; ++i) {
      const int row = erg*RE + i;
      const float4 p0 = *(const float4*)(bufX + row*HH + f0);
      const float4 p1v = *(const float4*)(bufY + row*HH + f0);
      const float ox = fmaxf(p0.x + p1v.x + b4.x, 0.f);
      const float oy = fmaxf(p0.y + p1v.y + b4.y, 0.f);
      const float oz = fmaxf(p0.z + p1v.z + b4.z, 0.f);
      const float ow = fmaxf(p0.w + p1v.w + b4.w, 0.f);
      float4 v; v.x=ox; v.y=oy; v.z=oz; v.w=ow;
      *(float4*)(bufX + row*HH + f0) = v;
      float p1 = ox*wn4.x + oy*wn4.y + oz*wn4.z + ow*wn4.w;
      float p2 = ox*wr4.x + oy*wr4.y + oz*wr4.z + ow*wr4.w;
#pragma unroll
      for (int off = 16; off >= 1; off >>= 1) {
        p1 += __shfl_xor(p1, off);
        p2 += __shfl_xor(p2, off);
      }
      if ((t & 31) == 0) { s_v1[row] = p1; s_v2[row] = p2; }
    }
  }
  __syncthreads();

  // P45 (wave 0): score -> rank -> inv -> edge remap
  if (t < 64) {
    if (t < M) {
      float sc = bs[0] + s_v2[t];
#pragma unroll
      for (int m0 = 0; m0 < M; m0 += 4) {
        const float4 a4 = *(const float4*)(s_A  + t*APAD + m0);
        const float4 v4 = *(const float4*)(s_v1 + m0);
        sc += a4.x*v4.x + a4.y*v4.y + a4.z*v4.z + a4.w*v4.w;
      }
      s_score[t] = tanhf(sc);
    }
    if (t < M) {
      const float st = s_score[t];
      int r = 0;
      for (int m = 0; m < M; ++m) {
        const float sm = s_score[m];
        r += (sm > st) || (sm == st && m < t);
      }
      s_rank[t] = r;
      if (r < KK) s_inv[r] = t;
    }
    if (!LAST) {
      const int a = s_rank[src_r];
      const int b = s_rank[dst_r];
      const bool val = (a < KK) && (b < KK);
      ew_r  = val ? ew_r : 0.f;
      src_r = val ? a : 0;
      dst_r = val ? b : 0;
    }
  }
  __syncthreads();

  // P6: readout (gmp || gap); zero A for next stage
  {
    const int f = t & 127, which = t >> 7;
    float r_acc = which ? 0.f : -INFINITY;
#pragma unroll
    for (int r = 0; r < KK; ++r) {
      const int n = s_inv[r];
      const float v = bufX[n*HH + f] * s_score[n];
      r_acc = which ? (r_acc + v) : fmaxf(r_acc, v);
    }
    featg[which*HH + f] = which ? r_acc * (1.f/KK) : r_acc;
  }
  if (!LAST) {
    for (int idx = t; idx < NN0*APAD/4; idx += 256) {
      float4 z4; z4.x = 0.f; z4.y = 0.f; z4.z = 0.f; z4.w = 0.f;
      *(float4*)(s_A + idx*4) = z4;
    }
  }
  __syncthreads();
}

__global__ __launch_bounds__(256, 5) void graph_kernel(
    const float* __restrict__ x,
    const int* __restrict__ esrc, const int* __restrict__ edst, const float* __restrict__ ewg,
    const float* __restrict__ W1, const float* __restrict__ b1,
    const float* __restrict__ Ws1r, const float* __restrict__ Ws1n, const float* __restrict__ bs1,
    const float* __restrict__ W2, const float* __restrict__ b2,
    const float* __restrict__ Ws2r, const float* __restrict__ Ws2n, const float* __restrict__ bs2,
    const float* __restrict__ W3, const float* __restrict__ b3,
    const float* __restrict__ Ws3r, const float* __restrict__ Ws3n, const float* __restrict__ bs3,
    float* __restrict__ feat)
{
  __shared__ __align__(16) float bufX[NN0*HH];
  __shared__ __align__(16) float bufY[2048];
  __shared__ __align__(16) float s_A[NN0*APAD];
  __shared__ __align__(16) float s_dis[NN0], s_cm[NN0], s_sc2[NN0];
  __shared__ __align__(16) float s_v1[NN0], s_v2[NN0], s_score[NN0];
  __shared__ __align__(16) int   s_rank[NN0], s_inv[NN0];

  const int t = threadIdx.x;
  const int g = blockIdx.x;

  for (int idx = t; idx < NN0*NFF/4; idx += 256)
    *(float4*)(bufX + idx*4) = *(const float4*)(x + (size_t)g*NN0*NFF + idx*4);
  int src_r, dst_r; float ew_r;
  {
    const int e = g*EE0 + (t & 63);
    src_r = esrc[e] - g*NN0;
    dst_r = edst[e] - g*NN0;
    ew_r  = ewg[e];
  }
  for (int idx = t; idx < NN0*APAD/4; idx += 256) {
    float4 z4; z4.x = 0.f; z4.y = 0.f; z4.z = 0.f; z4.w = 0.f;
    *(float4*)(s_A + idx*4) = z4;
  }
  __syncthreads();

  float* featg = feat + (size_t)g * SIXH;

  stage<NN0, 16, NFF, NFF, false, false>(W1, b1, Ws1r, Ws1n, bs1,
      bufX, bufY, s_A, s_dis, s_cm, s_sc2, s_v1, s_v2, s_score, s_rank, s_inv,
      src_r, dst_r, ew_r, featg, t);
  stage<16, 8, HH, HH, true, false>(W2, b2, Ws2r, Ws2n, bs2,
      bufX, bufY, s_A, s_dis, s_cm, s_sc2, s_v1, s_v2, s_score, s_rank, s_inv,
      src_r, dst_r, ew_r, featg + 256, t);
  stage<8, 4, HH, HH, true, true>(W3, b3, Ws3r, Ws3n, bs3,
      bufX, bufY, s_A, s_dis, s_cm, s_sc2, s_v1, s_v2, s_score, s_rank, s_inv,
      src_r, dst_r, ew_r, featg + 512, t);
}

// ============================================================
// DDI stage
// ============================================================

__global__ void k_deg_init(float* __restrict__ degf) {
  int i = blockIdx.x*256 + threadIdx.x;
  if (i < GG) degf[i] = 1.f;
}

__global__ void k_deg_acc(const int* __restrict__ ddi, float* __restrict__ degf) {
  int e = blockIdx.x*256 + threadIdx.x;
  if (e < E2B) atomicAdd(&degf[ddi[E2B + e]], 1.f);
}

// hdd = feat @ Wd; fused epilogue also writes z = hdd/deg + bd
__global__ __launch_bounds__(256, 4) void k_ddi_gemm(const float* __restrict__ feat,
    const float* __restrict__ Wd, const float* __restrict__ degf,
    const float* __restrict__ bd, float* __restrict__ hdd, float* __restrict__ z)
{
  __shared__ __align__(16) float s_f[12*SIXH];
  const int t = threadIdx.x;
  const int r0 = blockIdx.x * 12;
  const int cg = t & 63, rg = t >> 6;
  for (int idx = t; idx < 12*SIXH/4; idx += 256) {
    const int row = idx / 192;
    float4 v; v.x = 0.f; v.y = 0.f; v.z = 0.f; v.w = 0.f;
    if (r0 + row < GG) v = *(const float4*)(feat + (size_t)r0*SIXH + idx*4);
    *(float4*)(s_f + idx*4) = v;
  }
  __syncthreads();
  float acc[3][4];
#pragma unroll
  for (int i = 0; i < 3; ++i) { acc[i][0]=0.f; acc[i][1]=0.f; acc[i][2]=0.f; acc[i][3]=0.f; }
#pragma unroll 4
  for (int k = 0; k < SIXH; ++k) {
    const float4 w = *(const float4*)(Wd + (size_t)k*DD + cg*4);
#pragma unroll
    for (int i = 0; i < 3; ++i) {
      const float a = s_f[(rg*3 + i)*SIXH + k];
      acc[i][0]=fmaf(a,w.x,acc[i][0]); acc[i][1]=fmaf(a,w.y,acc[i][1]);
      acc[i][2]=fmaf(a,w.z,acc[i][2]); acc[i][3]=fmaf(a,w.w,acc[i][3]);
    }
  }
  const float4 bd4 = *(const float4*)(bd + cg*4);
#pragma unroll
  for (int i = 0; i < 3; ++i) {
    const int row = r0 + rg*3 + i;
    if (row < GG) {
      float4 v; v.x=acc[i][0]; v.y=acc[i][1]; v.z=acc[i][2]; v.w=acc[i][3];
      *(float4*)(hdd + (size_t)row*DD + cg*4) = v;
      const float rd = 1.f / degf[row];
      float4 zv;
      zv.x = fmaf(v.x, rd, bd4.x); zv.y = fmaf(v.y, rd, bd4.y);
      zv.z = fmaf(v.z, rd, bd4.z); zv.w = fmaf(v.w, rd, bd4.w);
      *(float4*)(z + (size_t)row*DD + cg*4) = zv;
    }
  }
}

// 4 edges per block: z[d] += rsqrt(deg_s)*rsqrt(deg_d)*hdd[s]
__global__ void k_scatter(const int* __restrict__ ddi, const float* __restrict__ degf,
                          const float* __restrict__ hdd, float* __restrict__ z)
{
  const int t = threadIdx.x;
#pragma unroll
  for (int j = 0; j < 4; ++j) {
    const int e = blockIdx.x*4 + j;
    const int s = ddi[e], d = ddi[E2B + e];
    const float nrm = rsqrtf(degf[s]) * rsqrtf(degf[d]);
    atomicAdd(&z[(size_t)d*DD + t], nrm * hdd[(size_t)s*DD + t]);
  }
}

// X = sigmoid(relu(z)@Wl1+bl1), Y = sigmoid(relu(z)@Wl2+bl2) for ALL graphs
__global__ __launch_bounds__(256) void k_xy(const float* __restrict__ z,
    const float* __restrict__ Wl1, const float* __restrict__ bl1,
    const float* __restrict__ Wl2, const float* __restrict__ bl2,
    float* __restrict__ X, float* __restrict__ Y)
{
  __shared__ __align__(16) float s_z[8*257];
  const int t = threadIdx.x;
  const int g0 = blockIdx.x * 8;
  for (int idx = t; idx < 8*256; idx += 256) {
    const int r = idx >> 8, k = idx & 255;
    s_z[r*257 + k] = fmaxf(z[(size_t)(g0 + r)*DD + k], 0.f);
  }
  __syncthreads();
  float acc[8];
#pragma unroll
  for (int r = 0; r < 8; ++r) acc[r] = bl1[t];
#pragma unroll 4
  for (int k = 0; k < 256; ++k) {
    const float w = Wl1[(size_t)k*DD + t];
#pragma unroll
    for (int r = 0; r < 8; ++r) acc[r] = fmaf(s_z[r*257 + k], w, acc[r]);
  }
#pragma unroll
  for (int r = 0; r < 8; ++r)
    X[(size_t)(g0 + r)*DD + t] = 1.f / (1.f + expf(-acc[r]));
#pragma unroll
  for (int r = 0; r < 8; ++r) acc[r] = bl2[t];
#pragma unroll 4
  for (int k = 0; k < 256; ++k) {
    const float w = Wl2[(size_t)k*DD + t];
#pragma unroll
    for (int r = 0; r < 8; ++r) acc[r] = fmaf(s_z[r*257 + k], w, acc[r]);
  }
#pragma unroll
  for (int r = 0; r < 8; ++r)
    Y[(size_t)(g0 + r)*DD + t] = 1.f / (1.f + expf(-acc[r]));
}

// per-edge: A = sigmoid(attr@Wl3+bl3); lp = X[s] + A - Y[d]; norms + pos_x
__global__ __launch_bounds__(256) void k_edge(const float* __restrict__ X,
    const float* __restrict__ Y, const int* __restrict__ ddi,
    const float* __restrict__ attr,
    const float* __restrict__ Wl3, const float* __restrict__ bl3,
    float* __restrict__ out)
{
  __shared__ __align__(16) float s_a[8*68];
  __shared__ __align__(16) float s_r[8*257];
  const int t = threadIdx.x;
  const int e0 = blockIdx.x * 8;
  for (int idx = t; idx < 8*64; idx += 256) {
    const int r = idx >> 6, k = idx & 63;
    s_a[r*68 + k] = attr[(size_t)(e0 + r)*NFF + k];
  }
  __syncthreads();
  float acc[8];
#pragma unroll
  for (int r = 0; r < 8; ++r) acc[r] = bl3[t];
#pragma unroll 4
  for (int k = 0; k < 64; ++k) {
    const float w = Wl3[(size_t)k*DD + t];
#pragma unroll
    for (int r = 0; r < 8; ++r) acc[r] = fmaf(s_a[r*68 + k], w, acc[r]);
  }
#pragma unroll
  for (int r = 0; r < 8; ++r) {
    const int e = e0 + r;
    const int s = ddi[e], d = ddi[E2B + e];
    const float xv = X[(size_t)s*DD + t];
    const float yv = Y[(size_t)d*DD + t];
    const float av = 1.f / (1.f + expf(-acc[r]));
    const float lp = xv + av - yv;
    s_r[r*257 + t] = lp * lp;
    if (e < BB) out[12288 + (size_t)e*DD + t] = xv;
  }
  __syncthreads();
  {
    const int row = t >> 5, l = t & 31;
    float s = 0.f;
#pragma unroll
    for (int j = 0; j < 8; ++j) s += s_r[row*257 + l + 32*j];
#pragma unroll
    for (int off = 16; off >= 1; off >>= 1) s += __shfl_xor(s, off);
    if (l == 0) {
      const float nrm = sqrtf(s);
      const int e = e0 + row;
      if (e < BB) out[4096 + e] = nrm;
      else        out[8192 + (e - BB)] = nrm;
    }
  }
}

__global__ void k_loss(float* __restrict__ out) {
  int i = blockIdx.x*256 + threadIdx.x;
  if (i < BB) out[i] = 2.f*(float)DD - out[4096 + i] + 0.5f*out[8192 + i];
}

// ============================================================

extern "C" void kernel_launch(void* const* d_in, const int* in_sizes, int n_in,
                              void* d_out, int out_size, void* d_ws, size_t ws_size,
                              hipStream_t stream)
{
  const float* x    = (const float*)d_in[0];
  const int*   esrc = (const int*)d_in[1];
  const int*   edst = (const int*)d_in[2];
  const float* ewt  = (const float*)d_in[3];
  const int*   ddi  = (const int*)d_in[4];
  const float* attr = (const float*)d_in[5];
  const float* W1   = (const float*)d_in[6];  const float* b1  = (const float*)d_in[7];
  const float* Ws1r = (const float*)d_in[8];  const float* Ws1n= (const float*)d_in[9];  const float* bs1 = (const float*)d_in[10];
  const float* W2   = (const float*)d_in[11]; const float* b2  = (const float*)d_in[12];
  const float* Ws2r = (const float*)d_in[13]; const float* Ws2n= (const float*)d_in[14]; const float* bs2 = (const float*)d_in[15];
  const float* W3   = (const float*)d_in[16]; const float* b3  = (const float*)d_in[17];
  const float* Ws3r = (const float*)d_in[18]; const float* Ws3n= (const float*)d_in[19]; const float* bs3 = (const float*)d_in[20];
  const float* Wd   = (const float*)d_in[21]; const float* bd  = (const float*)d_in[22];
  const float* Wl1  = (const float*)d_in[23]; const float* bl1 = (const float*)d_in[24];
  const float* Wl2  = (const float*)d_in[25]; const float* bl2 = (const float*)d_in[26];
  const float* Wl3  = (const float*)d_in[27]; const float* bl3 = (const float*)d_in[28];

  float* ws   = (float*)d_ws;
  float* feat = ws;                               // G*768
  float* hdd  = feat + (size_t)GG*SIXH;           // G*256
  float* zb   = hdd  + (size_t)GG*DD;             // G*256
  float* degf = zb   + (size_t)GG*DD;             // G
  float* Xb   = feat;                             // reuse feat region (dead after gemm)
  float* Yb   = feat + (size_t)GG*DD;
  float* out  = (float*)d_out;

  graph_kernel<<<GG, 256, 0, stream>>>(x, esrc, edst, ewt,
      W1, b1, Ws1r, Ws1n, bs1, W2, b2, Ws2r, Ws2n, bs2, W3, b3, Ws3r, Ws3n, bs3, feat);
  k_deg_init<<<(GG + 255)/256, 256, 0, stream>>>(degf);
  k_deg_acc<<<(E2B + 255)/256, 256, 0, stream>>>(ddi, degf);
  k_ddi_gemm<<<(GG + 11)/12, 256, 0, stream>>>(feat, Wd, degf, bd, hdd, zb);
  k_scatter<<<E2B/4, 256, 0, stream>>>(ddi, degf, hdd, zb);
  k_xy<<<GG/8, 256, 0, stream>>>(zb, Wl1, bl1, Wl2, bl2, Xb, Yb);
  k_edge<<<E2B/8, 256, 0, stream>>>(Xb, Yb, ddi, attr, Wl3, bl3, out);
  k_loss<<<(BB + 255)/256, 256, 0, stream>>>(out);
}

// Round 10
// 433.370 us; speedup vs baseline: 1.3099x; 1.2035x over previous
//
#include <hip/hip_runtime.h>
#include <math.h>

#define GG   10000
#define NN0  32
#define EE0  64
#define NFF  64
#define HH   128
#define DD   256
#define BB   4096
#define E2B  8192
#define SIXH 768
#define APAD 36

typedef unsigned short u16;
typedef __attribute__((ext_vector_type(8))) short short8v;
typedef __attribute__((ext_vector_type(4))) short short4v;
typedef __attribute__((ext_vector_type(4))) float f32x4;

static __device__ __forceinline__ u16 f2bf(float x) {
  unsigned u = __float_as_uint(x);
  return (u16)((u + 0x7FFFu + ((u >> 16) & 1u)) >> 16);   // RTNE
}
static __device__ __forceinline__ float bf2f(u16 h) {
  return __uint_as_float(((unsigned)h) << 16);
}

// ============================================================
// Per-graph fused pipeline (round-7 structure; feat written bf16).
// ============================================================

template<int M, int KK, int K, int SX, bool IND, bool LAST>
__device__ __forceinline__ void stage(
    const float* __restrict__ Wg, const float* __restrict__ bg,
    const float* __restrict__ Wr, const float* __restrict__ Wn, const float* __restrict__ bs,
    float* bufX, float* bufY, float* s_A,
    float* s_dis, float* s_cm, float* s_sc2,
    float* s_v1, float* s_v2, float* s_score, int* s_rank, int* s_inv,
    int& src_r, int& dst_r, float& ew_r,
    u16* __restrict__ featg, int t)
{
  // P0: raw A[dst][src] += ew via LDS atomics (wave 0, one edge per lane)
  if (t < EE0)
    atomicAdd(&s_A[dst_r*APAD + src_r], ew_r);
  __syncthreads();

  // P1: deg = 1 + row-sum(A) -> dis; cm = dis*g; sc2 = dis^2*g
  if (t < M) {
    float deg = 1.f;
#pragma unroll
    for (int m0 = 0; m0 < M; m0 += 4) {
      const float4 a4 = *(const float4*)(s_A + t*APAD + m0);
      deg += a4.x + a4.y + a4.z + a4.w;
    }
    const float dis = rsqrtf(deg);
    const float gg = IND ? s_score[s_inv[t]] : 1.f;
    s_dis[t] = dis; s_cm[t] = dis*gg; s_sc2[t] = dis*dis*gg;
  }
  __syncthreads();

  // P2: y[r] = dis_r * sum_m A[r,m]*cm[m]*x[ind(m)] + sc2[r]*x[ind(r)]
  {
    constexpr int CGB = K/4, RGB = 256/CGB, R = M/RGB;
    const int cg = t % CGB, rg = t / CGB;
    const int c0 = cg * 4;
    float acc[R][4];
#pragma unroll
    for (int i = 0; i < R; ++i) { acc[i][0]=0.f; acc[i][1]=0.f; acc[i][2]=0.f; acc[i][3]=0.f; }
#pragma unroll 2
    for (int m0 = 0; m0 < M; m0 += 4) {
      float4 a[R];
#pragma unroll
      for (int i = 0; i < R; ++i)
        a[i] = *(const float4*)(s_A + (rg*R + i)*APAD + m0);
#pragma unroll
      for (int j = 0; j < 4; ++j) {
        const int m = m0 + j;
        const int row = IND ? s_inv[m] : m;
        const float4 xv = *(const float4*)(bufX + row*SX + c0);
        const float cmm = s_cm[m];
#pragma unroll
        for (int i = 0; i < R; ++i) {
          const float aj = (j==0) ? a[i].x : (j==1) ? a[i].y : (j==2) ? a[i].z : a[i].w;
          const float cf = aj * cmm;
          acc[i][0] = fmaf(cf, xv.x, acc[i][0]);
          acc[i][1] = fmaf(cf, xv.y, acc[i][1]);
          acc[i][2] = fmaf(cf, xv.z, acc[i][2]);
          acc[i][3] = fmaf(cf, xv.w, acc[i][3]);
        }
      }
    }
#pragma unroll
    for (int i = 0; i < R; ++i) {
      const int r = rg*R + i;
      const int rr = IND ? s_inv[r] : r;
      const float4 xv = *(const float4*)(bufX + rr*SX + c0);
      const float dr = s_dis[r], sc = s_sc2[r];
      float4 v;
      v.x = fmaf(sc, xv.x, acc[i][0]*dr);
      v.y = fmaf(sc, xv.y, acc[i][1]*dr);
      v.z = fmaf(sc, xv.z, acc[i][2]*dr);
      v.w = fmaf(sc, xv.w, acc[i][3]*dr);
      *(float4*)(bufY + r*K + c0) = v;
    }
  }
  __syncthreads();

  // P3: out = relu(y @ W + b) -> bufX; fused v1 = out.Wn, v2 = out.Wr
  if constexpr (K != HH) {
    constexpr int R = M / 4;
    const int cg = t & 63;
    const int rg = t >> 6;
    float acc0[R], acc1[R];
#pragma unroll
    for (int i = 0; i < R; ++i) { acc0[i]=0.f; acc1[i]=0.f; }
#pragma unroll 2
    for (int k0 = 0; k0 < K; k0 += 4) {
      float4 yv[R];
#pragma unroll
      for (int i = 0; i < R; ++i)
        yv[i] = *(const float4*)(bufY + (rg*R + i)*K + k0);
#pragma unroll
      for (int j = 0; j < 4; ++j) {
        const float2 w = *(const float2*)(Wg + (size_t)(k0+j)*HH + cg*2);
#pragma unroll
        for (int i = 0; i < R; ++i) {
          const float yj = (j==0) ? yv[i].x : (j==1) ? yv[i].y : (j==2) ? yv[i].z : yv[i].w;
          acc0[i] = fmaf(yj, w.x, acc0[i]);
          acc1[i] = fmaf(yj, w.y, acc1[i]);
        }
      }
    }
    const float2 b2  = *(const float2*)(bg + cg*2);
    const float2 wn2 = *(const float2*)(Wn + cg*2);
    const float2 wr2 = *(const float2*)(Wr + cg*2);
#pragma unroll
    for (int i = 0; i < R; ++i) {
      const int row = rg*R + i;
      const float ox = fmaxf(acc0[i] + b2.x, 0.f);
      const float oy = fmaxf(acc1[i] + b2.y, 0.f);
      float2 v; v.x=ox; v.y=oy;
      *(float2*)(bufX + row*HH + cg*2) = v;
      float p1 = ox*wn2.x + oy*wn2.y;
      float p2 = ox*wr2.x + oy*wr2.y;
#pragma unroll
      for (int off = 32; off >= 1; off >>= 1) {
        p1 += __shfl_xor(p1, off);
        p2 += __shfl_xor(p2, off);
      }
      if ((t & 63) == 0) { s_v1[row] = p1; s_v2[row] = p2; }
    }
  } else {
    constexpr int R = M / 2;
    const int cg  = t & 63;
    const int sub = (t >> 6) & 1;
    const int pr  = t >> 7;
    const int kbase = pr * (K/2);
    float acc0[R], acc1[R];
#pragma unroll
    for (int i = 0; i < R; ++i) { acc0[i]=0.f; acc1[i]=0.f; }
#pragma unroll 2
    for (int k0 = 0; k0 < K/2; k0 += 4) {
      float4 yv[R];
#pragma unroll
      for (int i = 0; i < R; ++i)
        yv[i] = *(const float4*)(bufY + (sub*R + i)*K + kbase + k0);
#pragma unroll
      for (int j = 0; j < 4; ++j) {
        const float2 w = *(const float2*)(Wg + (size_t)(kbase+k0+j)*HH + cg*2);
#pragma unroll
        for (int i = 0; i < R; ++i) {
          const float yj = (j==0) ? yv[i].x : (j==1) ? yv[i].y : (j==2) ? yv[i].z : yv[i].w;
          acc0[i] = fmaf(yj, w.x, acc0[i]);
          acc1[i] = fmaf(yj, w.y, acc1[i]);
        }
      }
    }
    __syncthreads();
    float* pdst = pr ? bufY : bufX;
#pragma unroll
    for (int i = 0; i < R; ++i) {
      float2 v; v.x=acc0[i]; v.y=acc1[i];
      *(float2*)(pdst + (sub*R + i)*HH + cg*2) = v;
    }
    __syncthreads();
    constexpr int RE = M / 8;
    const int ecg = t & 31, erg = t >> 5;
    const int f0 = ecg * 4;
    const float4 b4  = *(const float4*)(bg + f0);
    const float4 wn4 = *(const float4*)(Wn + f0);
    const float4 wr4 = *(const float4*)(Wr + f0);
#pragma unroll
    for (int i = 0; i < RE; ++i) {
      const int row = erg*RE + i;
      const float4 p0 = *(const float4*)(bufX + row*HH + f0);
      const float4 p1v = *(const float4*)(bufY + row*HH + f0);
      const float ox = fmaxf(p0.x + p1v.x + b4.x, 0.f);
      const float oy = fmaxf(p0.y + p1v.y + b4.y, 0.f);
      const float oz = fmaxf(p0.z + p1v.z + b4.z, 0.f);
      const float ow = fmaxf(p0.w + p1v.w + b4.w, 0.f);
      float4 v; v.x=ox; v.y=oy; v.z=oz; v.w=ow;
      *(float4*)(bufX + row*HH + f0) = v;
      float p1 = ox*wn4.x + oy*wn4.y + oz*wn4.z + ow*wn4.w;
      float p2 = ox*wr4.x + oy*wr4.y + oz*wr4.z + ow*wr4.w;
#pragma unroll
      for (int off = 16; off >= 1; off >>= 1) {
        p1 += __shfl_xor(p1, off);
        p2 += __shfl_xor(p2, off);
      }
      if ((t & 31) == 0) { s_v1[row] = p1; s_v2[row] = p2; }
    }
  }
  __syncthreads();

  // P45 (wave 0): score -> rank -> inv -> edge remap
  if (t < 64) {
    if (t < M) {
      float sc = bs[0] + s_v2[t];
#pragma unroll
      for (int m0 = 0; m0 < M; m0 += 4) {
        const float4 a4 = *(const float4*)(s_A  + t*APAD + m0);
        const float4 v4 = *(const float4*)(s_v1 + m0);
        sc += a4.x*v4.x + a4.y*v4.y + a4.z*v4.z + a4.w*v4.w;
      }
      s_score[t] = tanhf(sc);
    }
    if (t < M) {
      const float st = s_score[t];
      int r = 0;
      for (int m = 0; m < M; ++m) {
        const float sm = s_score[m];
        r += (sm > st) || (sm == st && m < t);
      }
      s_rank[t] = r;
      if (r < KK) s_inv[r] = t;
    }
    if (!LAST) {
      const int a = s_rank[src_r];
      const int b = s_rank[dst_r];
      const bool val = (a < KK) && (b < KK);
      ew_r  = val ? ew_r : 0.f;
      src_r = val ? a : 0;
      dst_r = val ? b : 0;
    }
  }
  __syncthreads();

  // P6: readout (gmp || gap) -> bf16 feat; zero A for next stage
  {
    const int f = t & 127, which = t >> 7;
    float r_acc = which ? 0.f : -INFINITY;
#pragma unroll
    for (int r = 0; r < KK; ++r) {
      const int n = s_inv[r];
      const float v = bufX[n*HH + f] * s_score[n];
      r_acc = which ? (r_acc + v) : fmaxf(r_acc, v);
    }
    featg[which*HH + f] = f2bf(which ? r_acc * (1.f/KK) : r_acc);
  }
  if (!LAST) {
    for (int idx = t; idx < NN0*APAD/4; idx += 256) {
      float4 z4; z4.x = 0.f; z4.y = 0.f; z4.z = 0.f; z4.w = 0.f;
      *(float4*)(s_A + idx*4) = z4;
    }
  }
  __syncthreads();
}

__global__ __launch_bounds__(256, 5) void graph_kernel(
    const float* __restrict__ x,
    const int* __restrict__ esrc, const int* __restrict__ edst, const float* __restrict__ ewg,
    const float* __restrict__ W1, const float* __restrict__ b1,
    const float* __restrict__ Ws1r, const float* __restrict__ Ws1n, const float* __restrict__ bs1,
    const float* __restrict__ W2, const float* __restrict__ b2,
    const float* __restrict__ Ws2r, const float* __restrict__ Ws2n, const float* __restrict__ bs2,
    const float* __restrict__ W3, const float* __restrict__ b3,
    const float* __restrict__ Ws3r, const float* __restrict__ Ws3n, const float* __restrict__ bs3,
    u16* __restrict__ featB)
{
  __shared__ __align__(16) float bufX[NN0*HH];
  __shared__ __align__(16) float bufY[2048];
  __shared__ __align__(16) float s_A[NN0*APAD];
  __shared__ __align__(16) float s_dis[NN0], s_cm[NN0], s_sc2[NN0];
  __shared__ __align__(16) float s_v1[NN0], s_v2[NN0], s_score[NN0];
  __shared__ __align__(16) int   s_rank[NN0], s_inv[NN0];

  const int t = threadIdx.x;
  const int g = blockIdx.x;

  for (int idx = t; idx < NN0*NFF/4; idx += 256)
    *(float4*)(bufX + idx*4) = *(const float4*)(x + (size_t)g*NN0*NFF + idx*4);
  int src_r, dst_r; float ew_r;
  {
    const int e = g*EE0 + (t & 63);
    src_r = esrc[e] - g*NN0;
    dst_r = edst[e] - g*NN0;
    ew_r  = ewg[e];
  }
  for (int idx = t; idx < NN0*APAD/4; idx += 256) {
    float4 z4; z4.x = 0.f; z4.y = 0.f; z4.z = 0.f; z4.w = 0.f;
    *(float4*)(s_A + idx*4) = z4;
  }
  __syncthreads();

  u16* featg = featB + (size_t)g * SIXH;

  stage<NN0, 16, NFF, NFF, false, false>(W1, b1, Ws1r, Ws1n, bs1,
      bufX, bufY, s_A, s_dis, s_cm, s_sc2, s_v1, s_v2, s_score, s_rank, s_inv,
      src_r, dst_r, ew_r, featg, t);
  stage<16, 8, HH, HH, true, false>(W2, b2, Ws2r, Ws2n, bs2,
      bufX, bufY, s_A, s_dis, s_cm, s_sc2, s_v1, s_v2, s_score, s_rank, s_inv,
      src_r, dst_r, ew_r, featg + 256, t);
  stage<8, 4, HH, HH, true, true>(W3, b3, Ws3r, Ws3n, bs3,
      bufX, bufY, s_A, s_dis, s_cm, s_sc2, s_v1, s_v2, s_score, s_rank, s_inv,
      src_r, dst_r, ew_r, featg + 512, t);
}

// ============================================================
// DDI stage — bf16 MFMA GEMMs
// ============================================================

// convert+transpose weights: WdT[256][768], WlT[512][256] (col-major vs src)
__global__ void k_convW(const float* __restrict__ Wd,
                        const float* __restrict__ Wl1, const float* __restrict__ Wl2,
                        u16* __restrict__ WdT, u16* __restrict__ WlT)
{
  const int b = blockIdx.x, t = threadIdx.x;
  if (b < 256) {
#pragma unroll
    for (int i = 0; i < 3; ++i) {
      const int k = i*256 + t;
      WdT[(size_t)b*SIXH + k] = f2bf(Wd[(size_t)k*DD + b]);
    }
  } else {
    const int c = b - 256;
    const float* src = (c < 256) ? Wl1 : Wl2;
    WlT[(size_t)c*DD + t] = f2bf(src[(size_t)t*DD + (c & 255)]);
  }
}

__global__ void k_deg_init(float* __restrict__ degf) {
  int i = blockIdx.x*256 + threadIdx.x;
  if (i < GG) degf[i] = 1.f;
}

__global__ void k_deg_acc(const int* __restrict__ ddi, float* __restrict__ degf) {
  int e = blockIdx.x*256 + threadIdx.x;
  if (e < E2B) atomicAdd(&degf[ddi[E2B + e]], 1.f);
}

// hdd = feat @ Wd (bf16 MFMA); epilogue: z = hdd/deg + bd
__global__ __launch_bounds__(256) void k_ddi_mfma(const u16* __restrict__ featB,
    const u16* __restrict__ WdT, const float* __restrict__ degf,
    const float* __restrict__ bd, float* __restrict__ hdd, float* __restrict__ z)
{
  const int t = threadIdx.x;
  const int l = t & 63, w = t >> 6;
  const int r0 = blockIdx.x * 16;
  const int l15 = l & 15, kb = l >> 4;
  const int c0 = w * 64;
  f32x4 acc[4];
#pragma unroll
  for (int fi = 0; fi < 4; ++fi) { acc[fi][0]=0.f; acc[fi][1]=0.f; acc[fi][2]=0.f; acc[fi][3]=0.f; }
  const u16* aptr = featB + (size_t)(r0 + l15)*SIXH + kb*8;
#pragma unroll 2
  for (int kk = 0; kk < SIXH; kk += 32) {
    const short8v a = *(const short8v*)(aptr + kk);
#pragma unroll
    for (int fi = 0; fi < 4; ++fi) {
      const short8v b = *(const short8v*)(WdT + (size_t)(c0 + fi*16 + l15)*SIXH + kk + kb*8);
      acc[fi] = __builtin_amdgcn_mfma_f32_16x16x32_bf16(a, b, acc[fi], 0, 0, 0);
    }
  }
#pragma unroll
  for (int j = 0; j < 4; ++j) {
    const int gr = r0 + kb*4 + j;          // C/D row = (lane>>4)*4 + reg
    const float rd = 1.f / degf[gr];
#pragma unroll
    for (int fi = 0; fi < 4; ++fi) {
      const int c = c0 + fi*16 + l15;      // C/D col = lane&15
      const float v = acc[fi][j];
      hdd[(size_t)gr*DD + c] = v;
      z[(size_t)gr*DD + c] = fmaf(v, rd, bd[c]);
    }
  }
}

__global__ void k_scatter(const int* __restrict__ ddi, const float* __restrict__ degf,
                          const float* __restrict__ hdd, float* __restrict__ z)
{
  const int t = threadIdx.x;
#pragma unroll
  for (int j = 0; j < 4; ++j) {
    const int e = blockIdx.x*4 + j;
    const int s = ddi[e], d = ddi[E2B + e];
    const float nrm = rsqrtf(degf[s]) * rsqrtf(degf[d]);
    atomicAdd(&z[(size_t)d*DD + t], nrm * hdd[(size_t)s*DD + t]);
  }
}

// z -> bf16 hi + bf16 residual (for fp32-class MFMA accuracy)
__global__ void k_zsplit(const float* __restrict__ z,
                         u16* __restrict__ zh, u16* __restrict__ zl)
{
  const int i4 = blockIdx.x*256 + threadIdx.x;
  const float4 v = *(const float4*)(z + (size_t)i4*4);
  short4v h, lo;
  {
    const u16 h0 = f2bf(v.x); h[0] = (short)h0; lo[0] = (short)f2bf(v.x - bf2f(h0));
    const u16 h1 = f2bf(v.y); h[1] = (short)h1; lo[1] = (short)f2bf(v.y - bf2f(h1));
    const u16 h2 = f2bf(v.z); h[2] = (short)h2; lo[2] = (short)f2bf(v.z - bf2f(h2));
    const u16 h3 = f2bf(v.w); h[3] = (short)h3; lo[3] = (short)f2bf(v.w - bf2f(h3));
  }
  *(short4v*)(zh + (size_t)i4*4) = h;
  *(short4v*)(zl + (size_t)i4*4) = lo;
}

// [X|Y] = sigmoid((zh+zl) @ [Wl1|Wl2] + b)  (bf16 MFMA, split-A 2 passes)
__global__ __launch_bounds__(256) void k_xy_mfma(const u16* __restrict__ zh,
    const u16* __restrict__ zl, const u16* __restrict__ WlT,
    const float* __restrict__ bl1, const float* __restrict__ bl2,
    float* __restrict__ X, float* __restrict__ Y)
{
  const int t = threadIdx.x;
  const int l = t & 63, w = t >> 6;
  const int r0 = blockIdx.x * 16;
  const int l15 = l & 15, kb = l >> 4;
  const int c0 = w * 128;
  f32x4 acc[8];
#pragma unroll
  for (int fi = 0; fi < 8; ++fi) { acc[fi][0]=0.f; acc[fi][1]=0.f; acc[fi][2]=0.f; acc[fi][3]=0.f; }
  const u16* ah = zh + (size_t)(r0 + l15)*DD + kb*8;
  const u16* al = zl + (size_t)(r0 + l15)*DD + kb*8;
#pragma unroll 1
  for (int kk = 0; kk < DD; kk += 32) {
    const short8v a0 = *(const short8v*)(ah + kk);
    const short8v a1 = *(const short8v*)(al + kk);
#pragma unroll
    for (int fi = 0; fi < 8; ++fi) {
      const short8v b = *(const short8v*)(WlT + (size_t)(c0 + fi*16 + l15)*DD + kk + kb*8);
      acc[fi] = __builtin_amdgcn_mfma_f32_16x16x32_bf16(a0, b, acc[fi], 0, 0, 0);
      acc[fi] = __builtin_amdgcn_mfma_f32_16x16x32_bf16(a1, b, acc[fi], 0, 0, 0);
    }
  }
#pragma unroll
  for (int fi = 0; fi < 8; ++fi) {
    const int cg = c0 + fi*16 + l15;
    float* dst = (cg < 256) ? X : Y;
    const float bias = (cg < 256) ? bl1[cg] : bl2[cg - 256];
    const int c = cg & 255;
#pragma unroll
    for (int j = 0; j < 4; ++j) {
      const int gr = r0 + kb*4 + j;
      dst[(size_t)gr*DD + c] = 1.f / (1.f + expf(-(acc[fi][j] + bias)));
    }
  }
}

// per-edge: A = sigmoid(attr@Wl3+bl3); lp = X[s] + A - Y[d]; norms + pos_x
__global__ __launch_bounds__(256) void k_edge(const float* __restrict__ X,
    const float* __restrict__ Y, const int* __restrict__ ddi,
    const float* __restrict__ attr,
    const float* __restrict__ Wl3, const float* __restrict__ bl3,
    float* __restrict__ out)
{
  __shared__ __align__(16) float s_a[8*68];
  __shared__ __align__(16) float s_r[8*257];
  const int t = threadIdx.x;
  const int e0 = blockIdx.x * 8;
  for (int idx = t; idx < 8*64; idx += 256) {
    const int r = idx >> 6, k = idx & 63;
    s_a[r*68 + k] = attr[(size_t)(e0 + r)*NFF + k];
  }
  __syncthreads();
  float acc[8];
#pragma unroll
  for (int r = 0; r < 8; ++r) acc[r] = bl3[t];
#pragma unroll 4
  for (int k = 0; k < 64; ++k) {
    const float w = Wl3[(size_t)k*DD + t];
#pragma unroll
    for (int r = 0; r < 8; ++r) acc[r] = fmaf(s_a[r*68 + k], w, acc[r]);
  }
#pragma unroll
  for (int r = 0; r < 8; ++r) {
    const int e = e0 + r;
    const int s = ddi[e], d = ddi[E2B + e];
    const float xv = X[(size_t)s*DD + t];
    const float yv = Y[(size_t)d*DD + t];
    const float av = 1.f / (1.f + expf(-acc[r]));
    const float lp = xv + av - yv;
    s_r[r*257 + t] = lp * lp;
    if (e < BB) out[12288 + (size_t)e*DD + t] = xv;
  }
  __syncthreads();
  {
    const int row = t >> 5, l = t & 31;
    float s = 0.f;
#pragma unroll
    for (int j = 0; j < 8; ++j) s += s_r[row*257 + l + 32*j];
#pragma unroll
    for (int off = 16; off >= 1; off >>= 1) s += __shfl_xor(s, off);
    if (l == 0) {
      const float nrm = sqrtf(s);
      const int e = e0 + row;
      if (e < BB) out[4096 + e] = nrm;
      else        out[8192 + (e - BB)] = nrm;
    }
  }
}

__global__ void k_loss(float* __restrict__ out) {
  int i = blockIdx.x*256 + threadIdx.x;
  if (i < BB) out[i] = 2.f*(float)DD - out[4096 + i] + 0.5f*out[8192 + i];
}

// ============================================================

extern "C" void kernel_launch(void* const* d_in, const int* in_sizes, int n_in,
                              void* d_out, int out_size, void* d_ws, size_t ws_size,
                              hipStream_t stream)
{
  const float* x    = (const float*)d_in[0];
  const int*   esrc = (const int*)d_in[1];
  const int*   edst = (const int*)d_in[2];
  const float* ewt  = (const float*)d_in[3];
  const int*   ddi  = (const int*)d_in[4];
  const float* attr = (const float*)d_in[5];
  const float* W1   = (const float*)d_in[6];  const float* b1  = (const float*)d_in[7];
  const float* Ws1r = (const float*)d_in[8];  const float* Ws1n= (const float*)d_in[9];  const float* bs1 = (const float*)d_in[10];
  const float* W2   = (const float*)d_in[11]; const float* b2  = (const float*)d_in[12];
  const float* Ws2r = (const float*)d_in[13]; const float* Ws2n= (const float*)d_in[14]; const float* bs2 = (const float*)d_in[15];
  const float* W3   = (const float*)d_in[16]; const float* b3  = (const float*)d_in[17];
  const float* Ws3r = (const float*)d_in[18]; const float* Ws3n= (const float*)d_in[19]; const float* bs3 = (const float*)d_in[20];
  const float* Wd   = (const float*)d_in[21]; const float* bd  = (const float*)d_in[22];
  const float* Wl1  = (const float*)d_in[23]; const float* bl1 = (const float*)d_in[24];
  const float* Wl2  = (const float*)d_in[25]; const float* bl2 = (const float*)d_in[26];
  const float* Wl3  = (const float*)d_in[27]; const float* bl3 = (const float*)d_in[28];

  float* ws = (float*)d_ws;
  // layout (floats): featB 3.84M | hdd 2.56M | zb 2.56M | degf 10k | zh 1.28M | zl 1.28M | WdT | WlT
  u16*  featB = (u16*)ws;                          // GG*768 bf16
  float* hdd  = ws + 3840000;                      // GG*256 f32
  float* zb   = hdd + (size_t)GG*DD;
  float* degf = zb  + (size_t)GG*DD;
  u16*  zh    = (u16*)(degf + GG);                 // GG*256 bf16
  u16*  zl    = zh + (size_t)GG*DD;
  u16*  WdT   = zl + (size_t)GG*DD;                // 256*768 bf16
  u16*  WlT   = WdT + 256*SIXH;                    // 512*256 bf16
  float* Xb   = ws;                                // overlay featB (dead after ddi gemm)
  float* Yb   = hdd;                               // overlay hdd (dead after scatter)
  float* out  = (float*)d_out;

  k_convW<<<768, 256, 0, stream>>>(Wd, Wl1, Wl2, WdT, WlT);
  graph_kernel<<<GG, 256, 0, stream>>>(x, esrc, edst, ewt,
      W1, b1, Ws1r, Ws1n, bs1, W2, b2, Ws2r, Ws2n, bs2, W3, b3, Ws3r, Ws3n, bs3, featB);
  k_deg_init<<<(GG + 255)/256, 256, 0, stream>>>(degf);
  k_deg_acc<<<(E2B + 255)/256, 256, 0, stream>>>(ddi, degf);
  k_ddi_mfma<<<GG/16, 256, 0, stream>>>(featB, WdT, degf, bd, hdd, zb);
  k_scatter<<<E2B/4, 256, 0, stream>>>(ddi, degf, hdd, zb);
  k_zsplit<<<GG*DD/4/256, 256, 0, stream>>>(zb, zh, zl);
  k_xy_mfma<<<GG/16, 256, 0, stream>>>(zh, zl, WlT, bl1, bl2, Xb, Yb);
  k_edge<<<E2B/8, 256, 0, stream>>>(Xb, Yb, ddi, attr, Wl3, bl3, out);
  k_loss<<<(BB + 255)/256, 256, 0, stream>>>(out);
}

// Round 11
// 373.297 us; speedup vs baseline: 1.5207x; 1.1609x over previous
//
#include <hip/hip_runtime.h>
#include <math.h>

#define GG   10000
#define NN0  32
#define EE0  64
#define NFF  64
#define HH   128
#define DD   256
#define BB   4096
#define E2B  8192
#define SIXH 768
#define APAD 36

typedef unsigned short u16;
typedef __attribute__((ext_vector_type(8))) short short8v;
typedef __attribute__((ext_vector_type(4))) short short4v;
typedef __attribute__((ext_vector_type(4))) float f32x4;
typedef _Float16 h8f __attribute__((ext_vector_type(8)));
typedef _Float16 h4f __attribute__((ext_vector_type(4)));

static __device__ __forceinline__ u16 f2bf(float x) {
  unsigned u = __float_as_uint(x);
  return (u16)((u + 0x7FFFu + ((u >> 16) & 1u)) >> 16);   // RTNE
}
static __device__ __forceinline__ float bf2f(u16 h) {
  return __uint_as_float(((unsigned)h) << 16);
}

// ============================================================
// Per-graph fused pipeline. P3 (y@W) on MFMA via fp16 hi/lo split:
//   out = (yh)(Wh) + [(yh)(Wl') + (yl')(Wh)]/2048,  *l' = residual*2048
// Error ~2^-22 (fp32-class) -> top-k decisions preserved.
// v1/v2 via deterministic per-wave partial slots (no float atomics).
// ~32.0 KB LDS -> 5 blocks/CU.
// ============================================================

template<int M, int KK, int K, int SX, bool IND, bool LAST>
__device__ __forceinline__ void stage(
    const _Float16* __restrict__ WTh, const _Float16* __restrict__ WTl,
    const float* __restrict__ bg,
    const float* __restrict__ Wr, const float* __restrict__ Wn, const float* __restrict__ bs,
    float* bufX, _Float16* ybh, _Float16* ybl, float* s_A,
    float* s_dis, float* s_cm, float* s_sc2,
    float* s_v1p, float* s_v2p, float* s_score, int* s_rank, int* s_inv,
    int& src_r, int& dst_r, float& ew_r,
    u16* __restrict__ featg, int t)
{
  constexpr int KP = K + 8;
  constexpr int RT  = (M > 16) ? 2 : 1;
  constexpr int CTW = (RT == 2) ? 4 : 2;
  constexpr int KF  = K / 32;
  constexpr int NS  = (RT == 2) ? 2 : 4;

  // P0: raw A[dst][src] += ew via LDS atomics (wave 0, one edge per lane)
  if (t < EE0)
    atomicAdd(&s_A[dst_r*APAD + src_r], ew_r);
  __syncthreads();

  // P1: deg = 1 + row-sum(A) -> dis; cm = dis*g; sc2 = dis^2*g
  if (t < M) {
    float deg = 1.f;
#pragma unroll
    for (int m0 = 0; m0 < M; m0 += 4) {
      const float4 a4 = *(const float4*)(s_A + t*APAD + m0);
      deg += a4.x + a4.y + a4.z + a4.w;
    }
    const float dis = rsqrtf(deg);
    const float gg = IND ? s_score[s_inv[t]] : 1.f;
    s_dis[t] = dis; s_cm[t] = dis*gg; s_sc2[t] = dis*dis*gg;
  }
  __syncthreads();

  // P2: y[r] = dis_r * sum_m A[r,m]*cm[m]*x[ind(m)] + sc2[r]*x[ind(r)]
  //     written as fp16 hi + (residual*2048) lo
  {
    constexpr int CGB = K/4, RGB = 256/CGB, R = M/RGB;
    const int cg = t % CGB, rg = t / CGB;
    const int c0 = cg * 4;
    float acc[R][4];
#pragma unroll
    for (int i = 0; i < R; ++i) { acc[i][0]=0.f; acc[i][1]=0.f; acc[i][2]=0.f; acc[i][3]=0.f; }
#pragma unroll 2
    for (int m0 = 0; m0 < M; m0 += 4) {
      float4 a[R];
#pragma unroll
      for (int i = 0; i < R; ++i)
        a[i] = *(const float4*)(s_A + (rg*R + i)*APAD + m0);
#pragma unroll
      for (int j = 0; j < 4; ++j) {
        const int m = m0 + j;
        const int row = IND ? s_inv[m] : m;
        const float4 xv = *(const float4*)(bufX + row*SX + c0);
        const float cmm = s_cm[m];
#pragma unroll
        for (int i = 0; i < R; ++i) {
          const float aj = (j==0) ? a[i].x : (j==1) ? a[i].y : (j==2) ? a[i].z : a[i].w;
          const float cf = aj * cmm;
          acc[i][0] = fmaf(cf, xv.x, acc[i][0]);
          acc[i][1] = fmaf(cf, xv.y, acc[i][1]);
          acc[i][2] = fmaf(cf, xv.z, acc[i][2]);
          acc[i][3] = fmaf(cf, xv.w, acc[i][3]);
        }
      }
    }
#pragma unroll
    for (int i = 0; i < R; ++i) {
      const int r = rg*R + i;
      const int rr = IND ? s_inv[r] : r;
      const float4 xv = *(const float4*)(bufX + rr*SX + c0);
      const float dr = s_dis[r], sc = s_sc2[r];
      float4 v;
      v.x = fmaf(sc, xv.x, acc[i][0]*dr);
      v.y = fmaf(sc, xv.y, acc[i][1]*dr);
      v.z = fmaf(sc, xv.z, acc[i][2]*dr);
      v.w = fmaf(sc, xv.w, acc[i][3]*dr);
      h4f vh, vl;
      _Float16 h;
      h = (_Float16)v.x; vh[0] = h; vl[0] = (_Float16)((v.x - (float)h) * 2048.f);
      h = (_Float16)v.y; vh[1] = h; vl[1] = (_Float16)((v.y - (float)h) * 2048.f);
      h = (_Float16)v.z; vh[2] = h; vl[2] = (_Float16)((v.z - (float)h) * 2048.f);
      h = (_Float16)v.w; vh[3] = h; vl[3] = (_Float16)((v.w - (float)h) * 2048.f);
      *(h4f*)(ybh + r*KP + c0) = vh;
      *(h4f*)(ybl + r*KP + c0) = vl;
    }
  }
  __syncthreads();

  // P3 (MFMA): out = relu(y @ W + b) -> bufX; v1/v2 partials -> slots
  {
    const int l = t & 63, w = t >> 6;
    const int l15 = l & 15, kb = l >> 4;
    const int rt   = (RT == 2) ? (w >> 1) : 0;
    const int ct0  = (RT == 2) ? ((w & 1) * CTW) : (w * CTW);
    const int slot = (RT == 2) ? (w & 1) : w;

    h8f ah[KF], al[KF];
#pragma unroll
    for (int kf = 0; kf < KF; ++kf) {
      ah[kf] = *(const h8f*)(ybh + (rt*16 + l15)*KP + kf*32 + kb*8);
      al[kf] = *(const h8f*)(ybl + (rt*16 + l15)*KP + kf*32 + kb*8);
    }
    float p1[4] = {0.f,0.f,0.f,0.f}, p2[4] = {0.f,0.f,0.f,0.f};
#pragma unroll
    for (int ci = 0; ci < CTW; ++ci) {
      const int ct = ct0 + ci;
      const int col = ct*16 + l15;
      f32x4 a0 = {0.f,0.f,0.f,0.f}, a1 = {0.f,0.f,0.f,0.f};
#pragma unroll
      for (int kf = 0; kf < KF; ++kf) {
        const h8f bh = *(const h8f*)(WTh + (size_t)col*K + kf*32 + kb*8);
        const h8f bl = *(const h8f*)(WTl + (size_t)col*K + kf*32 + kb*8);
        a0 = __builtin_amdgcn_mfma_f32_16x16x32_f16(ah[kf], bh, a0, 0, 0, 0);
        a1 = __builtin_amdgcn_mfma_f32_16x16x32_f16(ah[kf], bl, a1, 0, 0, 0);
        a1 = __builtin_amdgcn_mfma_f32_16x16x32_f16(al[kf], bh, a1, 0, 0, 0);
      }
      const float bb = bg[col], wnc = Wn[col], wrc = Wr[col];
#pragma unroll
      for (int j = 0; j < 4; ++j) {
        const int row = rt*16 + kb*4 + j;
        const float o = fmaxf(fmaf(a1[j], (1.f/2048.f), a0[j]) + bb, 0.f);
        bufX[row*HH + col] = o;
        p1[j] = fmaf(o, wnc, p1[j]);
        p2[j] = fmaf(o, wrc, p2[j]);
      }
    }
#pragma unroll
    for (int j = 0; j < 4; ++j) {
#pragma unroll
      for (int off = 8; off >= 1; off >>= 1) {
        p1[j] += __shfl_xor(p1[j], off);
        p2[j] += __shfl_xor(p2[j], off);
      }
    }
    if (l15 == 0) {
#pragma unroll
      for (int j = 0; j < 4; ++j) {
        const int row = rt*16 + kb*4 + j;
        s_v1p[slot*32 + row] = p1[j];
        s_v2p[slot*32 + row] = p2[j];
      }
    }
  }
  __syncthreads();

  // P45 (wave 0): score -> rank -> inv -> edge remap  (slot-sum, deterministic)
  if (t < 64) {
    if (t < M) {
      float v2t = s_v2p[t] + s_v2p[32 + t];
      if (NS == 4) v2t += s_v2p[64 + t] + s_v2p[96 + t];
      float sc = bs[0] + v2t;
#pragma unroll
      for (int m0 = 0; m0 < M; m0 += 4) {
        const float4 a4 = *(const float4*)(s_A + t*APAD + m0);
        float4 v4 = *(const float4*)(s_v1p + m0);
        const float4 vb = *(const float4*)(s_v1p + 32 + m0);
        v4.x += vb.x; v4.y += vb.y; v4.z += vb.z; v4.w += vb.w;
        if (NS == 4) {
          const float4 vc = *(const float4*)(s_v1p + 64 + m0);
          const float4 vd = *(const float4*)(s_v1p + 96 + m0);
          v4.x += vc.x + vd.x; v4.y += vc.y + vd.y;
          v4.z += vc.z + vd.z; v4.w += vc.w + vd.w;
        }
        sc += a4.x*v4.x + a4.y*v4.y + a4.z*v4.z + a4.w*v4.w;
      }
      s_score[t] = tanhf(sc);
    }
    if (t < M) {
      const float st = s_score[t];
      int r = 0;
      for (int m = 0; m < M; ++m) {
        const float sm = s_score[m];
        r += (sm > st) || (sm == st && m < t);
      }
      s_rank[t] = r;
      if (r < KK) s_inv[r] = t;
    }
    if (!LAST) {
      const int a = s_rank[src_r];
      const int b = s_rank[dst_r];
      const bool val = (a < KK) && (b < KK);
      ew_r  = val ? ew_r : 0.f;
      src_r = val ? a : 0;
      dst_r = val ? b : 0;
    }
  }
  __syncthreads();

  // P6: readout (gmp || gap) -> bf16 feat; zero A for next stage
  {
    const int f = t & 127, which = t >> 7;
    float r_acc = which ? 0.f : -INFINITY;
#pragma unroll
    for (int r = 0; r < KK; ++r) {
      const int n = s_inv[r];
      const float v = bufX[n*HH + f] * s_score[n];
      r_acc = which ? (r_acc + v) : fmaxf(r_acc, v);
    }
    featg[which*HH + f] = f2bf(which ? r_acc * (1.f/KK) : r_acc);
  }
  if (!LAST) {
    for (int idx = t; idx < NN0*APAD/4; idx += 256) {
      float4 z4; z4.x = 0.f; z4.y = 0.f; z4.z = 0.f; z4.w = 0.f;
      *(float4*)(s_A + idx*4) = z4;
    }
  }
  __syncthreads();
}

__global__ __launch_bounds__(256, 5) void graph_kernel(
    const float* __restrict__ x,
    const int* __restrict__ esrc, const int* __restrict__ edst, const float* __restrict__ ewg,
    const _Float16* __restrict__ WT,
    const float* __restrict__ b1,
    const float* __restrict__ Ws1r, const float* __restrict__ Ws1n, const float* __restrict__ bs1,
    const float* __restrict__ b2,
    const float* __restrict__ Ws2r, const float* __restrict__ Ws2n, const float* __restrict__ bs2,
    const float* __restrict__ b3,
    const float* __restrict__ Ws3r, const float* __restrict__ Ws3n, const float* __restrict__ bs3,
    u16* __restrict__ featB)
{
  __shared__ __align__(16) float bufX[NN0*HH];          // 16 KB
  __shared__ __align__(16) _Float16 ybh[2304], ybl[2304]; // 9 KB
  __shared__ __align__(16) float s_A[NN0*APAD];         // 4.5 KB
  __shared__ __align__(16) float s_dis[NN0], s_cm[NN0], s_sc2[NN0], s_score[NN0];
  __shared__ __align__(16) float s_v1p[128], s_v2p[128];
  __shared__ __align__(16) int   s_rank[NN0], s_inv[NN0];

  const int t = threadIdx.x;
  const int g = blockIdx.x;

  for (int idx = t; idx < NN0*NFF/4; idx += 256)
    *(float4*)(bufX + idx*4) = *(const float4*)(x + (size_t)g*NN0*NFF + idx*4);
  int src_r, dst_r; float ew_r;
  {
    const int e = g*EE0 + (t & 63);
    src_r = esrc[e] - g*NN0;
    dst_r = edst[e] - g*NN0;
    ew_r  = ewg[e];
  }
  for (int idx = t; idx < NN0*APAD/4; idx += 256) {
    float4 z4; z4.x = 0.f; z4.y = 0.f; z4.z = 0.f; z4.w = 0.f;
    *(float4*)(s_A + idx*4) = z4;
  }
  __syncthreads();

  u16* featg = featB + (size_t)g * SIXH;
  const _Float16* W1h = WT;
  const _Float16* W1l = W1h + 128*64;
  const _Float16* W2h = W1l + 128*64;
  const _Float16* W2l = W2h + 128*128;
  const _Float16* W3h = W2l + 128*128;
  const _Float16* W3l = W3h + 128*128;

  stage<NN0, 16, NFF, NFF, false, false>(W1h, W1l, b1, Ws1r, Ws1n, bs1,
      bufX, ybh, ybl, s_A, s_dis, s_cm, s_sc2, s_v1p, s_v2p, s_score, s_rank, s_inv,
      src_r, dst_r, ew_r, featg, t);
  stage<16, 8, HH, HH, true, false>(W2h, W2l, b2, Ws2r, Ws2n, bs2,
      bufX, ybh, ybl, s_A, s_dis, s_cm, s_sc2, s_v1p, s_v2p, s_score, s_rank, s_inv,
      src_r, dst_r, ew_r, featg + 256, t);
  stage<8, 4, HH, HH, true, true>(W3h, W3l, b3, Ws3r, Ws3n, bs3,
      bufX, ybh, ybl, s_A, s_dis, s_cm, s_sc2, s_v1p, s_v2p, s_score, s_rank, s_inv,
      src_r, dst_r, ew_r, featg + 512, t);
}

// convert graph-stage weights into fp16 hi/lo, fragment-transposed [col][k]
__global__ void k_convW123(const float* __restrict__ W1, const float* __restrict__ W2,
                           const float* __restrict__ W3, _Float16* __restrict__ T)
{
  const int c = blockIdx.x;     // 0..127 output col
  const int k = threadIdx.x;    // 0..127
  _Float16* W1h = T;
  _Float16* W1l = W1h + 128*64;
  _Float16* W2h = W1l + 128*64;
  _Float16* W2l = W2h + 128*128;
  _Float16* W3h = W2l + 128*128;
  _Float16* W3l = W3h + 128*128;
  if (k < 64) {
    const float v = W1[(size_t)k*HH + c];
    const _Float16 h = (_Float16)v;
    W1h[c*64 + k] = h;
    W1l[c*64 + k] = (_Float16)((v - (float)h) * 2048.f);
  }
  {
    const float v = W2[(size_t)k*HH + c];
    const _Float16 h = (_Float16)v;
    W2h[c*HH + k] = h;
    W2l[c*HH + k] = (_Float16)((v - (float)h) * 2048.f);
  }
  {
    const float v = W3[(size_t)k*HH + c];
    const _Float16 h = (_Float16)v;
    W3h[c*HH + k] = h;
    W3l[c*HH + k] = (_Float16)((v - (float)h) * 2048.f);
  }
}

// ============================================================
// DDI stage — bf16 MFMA GEMMs (unchanged from round 10)
// ============================================================

__global__ void k_convW(const float* __restrict__ Wd,
                        const float* __restrict__ Wl1, const float* __restrict__ Wl2,
                        u16* __restrict__ WdT, u16* __restrict__ WlT)
{
  const int b = blockIdx.x, t = threadIdx.x;
  if (b < 256) {
#pragma unroll
    for (int i = 0; i < 3; ++i) {
      const int k = i*256 + t;
      WdT[(size_t)b*SIXH + k] = f2bf(Wd[(size_t)k*DD + b]);
    }
  } else {
    const int c = b - 256;
    const float* src = (c < 256) ? Wl1 : Wl2;
    WlT[(size_t)c*DD + t] = f2bf(src[(size_t)t*DD + (c & 255)]);
  }
}

__global__ void k_deg_init(float* __restrict__ degf) {
  int i = blockIdx.x*256 + threadIdx.x;
  if (i < GG) degf[i] = 1.f;
}

__global__ void k_deg_acc(const int* __restrict__ ddi, float* __restrict__ degf) {
  int e = blockIdx.x*256 + threadIdx.x;
  if (e < E2B) atomicAdd(&degf[ddi[E2B + e]], 1.f);
}

__global__ __launch_bounds__(256) void k_ddi_mfma(const u16* __restrict__ featB,
    const u16* __restrict__ WdT, const float* __restrict__ degf,
    const float* __restrict__ bd, float* __restrict__ hdd, float* __restrict__ z)
{
  const int t = threadIdx.x;
  const int l = t & 63, w = t >> 6;
  const int r0 = blockIdx.x * 16;
  const int l15 = l & 15, kb = l >> 4;
  const int c0 = w * 64;
  f32x4 acc[4];
#pragma unroll
  for (int fi = 0; fi < 4; ++fi) { acc[fi][0]=0.f; acc[fi][1]=0.f; acc[fi][2]=0.f; acc[fi][3]=0.f; }
  const u16* aptr = featB + (size_t)(r0 + l15)*SIXH + kb*8;
#pragma unroll 2
  for (int kk = 0; kk < SIXH; kk += 32) {
    const short8v a = *(const short8v*)(aptr + kk);
#pragma unroll
    for (int fi = 0; fi < 4; ++fi) {
      const short8v b = *(const short8v*)(WdT + (size_t)(c0 + fi*16 + l15)*SIXH + kk + kb*8);
      acc[fi] = __builtin_amdgcn_mfma_f32_16x16x32_bf16(a, b, acc[fi], 0, 0, 0);
    }
  }
#pragma unroll
  for (int j = 0; j < 4; ++j) {
    const int gr = r0 + kb*4 + j;
    const float rd = 1.f / degf[gr];
#pragma unroll
    for (int fi = 0; fi < 4; ++fi) {
      const int c = c0 + fi*16 + l15;
      const float v = acc[fi][j];
      hdd[(size_t)gr*DD + c] = v;
      z[(size_t)gr*DD + c] = fmaf(v, rd, bd[c]);
    }
  }
}

__global__ void k_scatter(const int* __restrict__ ddi, const float* __restrict__ degf,
                          const float* __restrict__ hdd, float* __restrict__ z)
{
  const int t = threadIdx.x;
#pragma unroll
  for (int j = 0; j < 4; ++j) {
    const int e = blockIdx.x*4 + j;
    const int s = ddi[e], d = ddi[E2B + e];
    const float nrm = rsqrtf(degf[s]) * rsqrtf(degf[d]);
    atomicAdd(&z[(size_t)d*DD + t], nrm * hdd[(size_t)s*DD + t]);
  }
}

__global__ void k_zsplit(const float* __restrict__ z,
                         u16* __restrict__ zh, u16* __restrict__ zl)
{
  const int i4 = blockIdx.x*256 + threadIdx.x;
  const float4 v = *(const float4*)(z + (size_t)i4*4);
  short4v h, lo;
  {
    const u16 h0 = f2bf(v.x); h[0] = (short)h0; lo[0] = (short)f2bf(v.x - bf2f(h0));
    const u16 h1 = f2bf(v.y); h[1] = (short)h1; lo[1] = (short)f2bf(v.y - bf2f(h1));
    const u16 h2 = f2bf(v.z); h[2] = (short)h2; lo[2] = (short)f2bf(v.z - bf2f(h2));
    const u16 h3 = f2bf(v.w); h[3] = (short)h3; lo[3] = (short)f2bf(v.w - bf2f(h3));
  }
  *(short4v*)(zh + (size_t)i4*4) = h;
  *(short4v*)(zl + (size_t)i4*4) = lo;
}

__global__ __launch_bounds__(256) void k_xy_mfma(const u16* __restrict__ zh,
    const u16* __restrict__ zl, const u16* __restrict__ WlT,
    const float* __restrict__ bl1, const float* __restrict__ bl2,
    float* __restrict__ X, float* __restrict__ Y)
{
  const int t = threadIdx.x;
  const int l = t & 63, w = t >> 6;
  const int r0 = blockIdx.x * 16;
  const int l15 = l & 15, kb = l >> 4;
  const int c0 = w * 128;
  f32x4 acc[8];
#pragma unroll
  for (int fi = 0; fi < 8; ++fi) { acc[fi][0]=0.f; acc[fi][1]=0.f; acc[fi][2]=0.f; acc[fi][3]=0.f; }
  const u16* ah = zh + (size_t)(r0 + l15)*DD + kb*8;
  const u16* al = zl + (size_t)(r0 + l15)*DD + kb*8;
#pragma unroll 1
  for (int kk = 0; kk < DD; kk += 32) {
    const short8v a0 = *(const short8v*)(ah + kk);
    const short8v a1 = *(const short8v*)(al + kk);
#pragma unroll
    for (int fi = 0; fi < 8; ++fi) {
      const short8v b = *(const short8v*)(WlT + (size_t)(c0 + fi*16 + l15)*DD + kk + kb*8);
      acc[fi] = __builtin_amdgcn_mfma_f32_16x16x32_bf16(a0, b, acc[fi], 0, 0, 0);
      acc[fi] = __builtin_amdgcn_mfma_f32_16x16x32_bf16(a1, b, acc[fi], 0, 0, 0);
    }
  }
#pragma unroll
  for (int fi = 0; fi < 8; ++fi) {
    const int cg = c0 + fi*16 + l15;
    float* dst = (cg < 256) ? X : Y;
    const float bias = (cg < 256) ? bl1[cg] : bl2[cg - 256];
    const int c = cg & 255;
#pragma unroll
    for (int j = 0; j < 4; ++j) {
      const int gr = r0 + kb*4 + j;
      dst[(size_t)gr*DD + c] = 1.f / (1.f + expf(-(acc[fi][j] + bias)));
    }
  }
}

__global__ __launch_bounds__(256) void k_edge(const float* __restrict__ X,
    const float* __restrict__ Y, const int* __restrict__ ddi,
    const float* __restrict__ attr,
    const float* __restrict__ Wl3, const float* __restrict__ bl3,
    float* __restrict__ out)
{
  __shared__ __align__(16) float s_a[8*68];
  __shared__ __align__(16) float s_r[8*257];
  const int t = threadIdx.x;
  const int e0 = blockIdx.x * 8;
  for (int idx = t; idx < 8*64; idx += 256) {
    const int r = idx >> 6, k = idx & 63;
    s_a[r*68 + k] = attr[(size_t)(e0 + r)*NFF + k];
  }
  __syncthreads();
  float acc[8];
#pragma unroll
  for (int r = 0; r < 8; ++r) acc[r] = bl3[t];
#pragma unroll 4
  for (int k = 0; k < 64; ++k) {
    const float w = Wl3[(size_t)k*DD + t];
#pragma unroll
    for (int r = 0; r < 8; ++r) acc[r] = fmaf(s_a[r*68 + k], w, acc[r]);
  }
#pragma unroll
  for (int r = 0; r < 8; ++r) {
    const int e = e0 + r;
    const int s = ddi[e], d = ddi[E2B + e];
    const float xv = X[(size_t)s*DD + t];
    const float yv = Y[(size_t)d*DD + t];
    const float av = 1.f / (1.f + expf(-acc[r]));
    const float lp = xv + av - yv;
    s_r[r*257 + t] = lp * lp;
    if (e < BB) out[12288 + (size_t)e*DD + t] = xv;
  }
  __syncthreads();
  {
    const int row = t >> 5, l = t & 31;
    float s = 0.f;
#pragma unroll
    for (int j = 0; j < 8; ++j) s += s_r[row*257 + l + 32*j];
#pragma unroll
    for (int off = 16; off >= 1; off >>= 1) s += __shfl_xor(s, off);
    if (l == 0) {
      const float nrm = sqrtf(s);
      const int e = e0 + row;
      if (e < BB) out[4096 + e] = nrm;
      else        out[8192 + (e - BB)] = nrm;
    }
  }
}

__global__ void k_loss(float* __restrict__ out) {
  int i = blockIdx.x*256 + threadIdx.x;
  if (i < BB) out[i] = 2.f*(float)DD - out[4096 + i] + 0.5f*out[8192 + i];
}

// ============================================================

extern "C" void kernel_launch(void* const* d_in, const int* in_sizes, int n_in,
                              void* d_out, int out_size, void* d_ws, size_t ws_size,
                              hipStream_t stream)
{
  const float* x    = (const float*)d_in[0];
  const int*   esrc = (const int*)d_in[1];
  const int*   edst = (const int*)d_in[2];
  const float* ewt  = (const float*)d_in[3];
  const int*   ddi  = (const int*)d_in[4];
  const float* attr = (const float*)d_in[5];
  const float* W1   = (const float*)d_in[6];  const float* b1  = (const float*)d_in[7];
  const float* Ws1r = (const float*)d_in[8];  const float* Ws1n= (const float*)d_in[9];  const float* bs1 = (const float*)d_in[10];
  const float* W2   = (const float*)d_in[11]; const float* b2  = (const float*)d_in[12];
  const float* Ws2r = (const float*)d_in[13]; const float* Ws2n= (const float*)d_in[14]; const float* bs2 = (const float*)d_in[15];
  const float* W3   = (const float*)d_in[16]; const float* b3  = (const float*)d_in[17];
  const float* Ws3r = (const float*)d_in[18]; const float* Ws3n= (const float*)d_in[19]; const float* bs3 = (const float*)d_in[20];
  const float* Wd   = (const float*)d_in[21]; const float* bd  = (const float*)d_in[22];
  const float* Wl1  = (const float*)d_in[23]; const float* bl1 = (const float*)d_in[24];
  const float* Wl2  = (const float*)d_in[25]; const float* bl2 = (const float*)d_in[26];
  const float* Wl3  = (const float*)d_in[27]; const float* bl3 = (const float*)d_in[28];

  float* ws = (float*)d_ws;
  u16*  featB = (u16*)ws;                          // GG*768 bf16
  float* hdd  = ws + 3840000;                      // GG*256 f32
  float* zb   = hdd + (size_t)GG*DD;
  float* degf = zb  + (size_t)GG*DD;
  u16*  zh    = (u16*)(degf + GG);                 // GG*256 bf16
  u16*  zl    = zh + (size_t)GG*DD;
  u16*  WdT   = zl + (size_t)GG*DD;                // 256*768 bf16
  u16*  WlT   = WdT + 256*SIXH;                    // 512*256 bf16
  _Float16* WgT = (_Float16*)(WlT + 512*DD);       // 81920 fp16 (graph W splits)
  float* Xb   = ws;                                // overlay featB (dead after ddi gemm)
  float* Yb   = hdd;                               // overlay hdd (dead after scatter)
  float* out  = (float*)d_out;

  k_convW<<<768, 256, 0, stream>>>(Wd, Wl1, Wl2, WdT, WlT);
  k_convW123<<<128, 128, 0, stream>>>(W1, W2, W3, WgT);
  graph_kernel<<<GG, 256, 0, stream>>>(x, esrc, edst, ewt, WgT,
      b1, Ws1r, Ws1n, bs1, b2, Ws2r, Ws2n, bs2, b3, Ws3r, Ws3n, bs3, featB);
  k_deg_init<<<(GG + 255)/256, 256, 0, stream>>>(degf);
  k_deg_acc<<<(E2B + 255)/256, 256, 0, stream>>>(ddi, degf);
  k_ddi_mfma<<<GG/16, 256, 0, stream>>>(featB, WdT, degf, bd, hdd, zb);
  k_scatter<<<E2B/4, 256, 0, stream>>>(ddi, degf, hdd, zb);
  k_zsplit<<<GG*DD/4/256, 256, 0, stream>>>(zb, zh, zl);
  k_xy_mfma<<<GG/16, 256, 0, stream>>>(zh, zl, WlT, bl1, bl2, Xb, Yb);
  k_edge<<<E2B/8, 256, 0, stream>>>(Xb, Yb, ddi, attr, Wl3, bl3, out);
  k_loss<<<(BB + 255)/256, 256, 0, stream>>>(out);
}